// Round 1
// baseline (5583.805 us; speedup 1.0000x reference)
//
#include <hip/hip_runtime.h>
#include <math.h>

constexpr int CB  = 8;     // batches
constexpr int CN  = 8192;  // points
constexpr int CS  = 512;   // npoint
constexpr int CK  = 32;    // nsample
constexpr int CD  = 128;   // dim
constexpr int CHD = 16;    // head dim
constexpr int CF  = 256;   // dff
constexpr int CO  = 256;   // dim_out
constexpr float CEPS = 1e-5f;

// ---------------------------------------------------------------- FPS
__global__ __launch_bounds__(1024)
void fps_kernel(const float* __restrict__ xyz, int* __restrict__ fps_idx)
{
#pragma clang fp contract(off)
  __shared__ float4 p4[CN];            // 128 KB
  __shared__ float wbest[16];
  __shared__ int   widx[16];
  __shared__ int   far_sh;
  const int b = blockIdx.x, t = threadIdx.x;
  const float* xb = xyz + (size_t)b*3*CN;
  for (int i = t; i < CN; i += 1024)
    p4[i] = make_float4(xb[i], xb[CN+i], xb[2*CN+i], 0.f);
  float dist[8];
  #pragma unroll
  for (int j=0;j<8;j++) dist[j] = 1e10f;
  __syncthreads();
  int far = 0;
  for (int it = 0; it < CS; ++it){
    if (t == 0) fps_idx[b*CS + it] = far;
    const float4 c = p4[far];
    float best = -1.f; int bi = 0;
    #pragma unroll
    for (int j=0;j<8;j++){
      const int i = t + 1024*j;
      const float4 p = p4[i];
      const float dx = p.x - c.x, dy = p.y - c.y, dz = p.z - c.z;
      const float d2 = (dx*dx + dy*dy) + dz*dz;
      const float nd = fminf(dist[j], d2);
      dist[j] = nd;
      if (nd > best){ best = nd; bi = i; }
    }
    #pragma unroll
    for (int off=32; off>=1; off>>=1){
      const float ob = __shfl_xor(best, off);
      const int   oi = __shfl_xor(bi, off);
      if (ob > best || (ob == best && oi < bi)){ best = ob; bi = oi; }
    }
    if ((t & 63) == 0){ wbest[t>>6] = best; widx[t>>6] = bi; }
    __syncthreads();
    if (t < 16){
      best = wbest[t]; bi = widx[t];
      #pragma unroll
      for (int off=8; off>=1; off>>=1){
        const float ob = __shfl_xor(best, off);
        const int   oi = __shfl_xor(bi, off);
        if (ob > best || (ob == best && oi < bi)){ best = ob; bi = oi; }
      }
      if (t == 0) far_sh = bi;
    }
    __syncthreads();
    far = far_sh;
  }
}

// ---------------------------------------------------------------- kNN top-32
__global__ __launch_bounds__(256)
void knn_kernel(const float* __restrict__ xyz, const int* __restrict__ fps_idx,
                int* __restrict__ gidx)
{
#pragma clang fp contract(off)
  __shared__ float wv[4];
  __shared__ int   wi[4];
  __shared__ int   win_sh;
  const int blk = blockIdx.x, t = threadIdx.x;
  const int b = blk >> 9, s = blk & 511;
  const float* xb = xyz + (size_t)b*3*CN;
  const int cidx = fps_idx[b*CS + s];
  const float cx = xb[cidx], cy = xb[CN+cidx], cz = xb[2*CN+cidx];
  const float cn2 = (cx*cx + cy*cy) + cz*cz;
  float dv[32];
  float mv = 1e30f; int mi = 0;
  #pragma unroll
  for (int j=0;j<32;j++){
    const int i = t + 256*j;
    const float x = xb[i], y = xb[CN+i], z = xb[2*CN+i];
    const float pn2 = (x*x + y*y) + z*z;
    const float dot = (cx*x + cy*y) + cz*z;
    const float d2 = (cn2 + pn2) - 2.0f*dot;
    dv[j] = d2;
    if (d2 < mv || (d2 == mv && i < mi)){ mv = d2; mi = i; }
  }
  for (int k=0;k<CK;k++){
    float v = mv; int i = mi;
    #pragma unroll
    for (int off=32; off>=1; off>>=1){
      const float ov = __shfl_xor(v, off);
      const int   oi = __shfl_xor(i, off);
      if (ov < v || (ov == v && oi < i)){ v = ov; i = oi; }
    }
    if ((t & 63) == 0){ wv[t>>6] = v; wi[t>>6] = i; }
    __syncthreads();
    if (t == 0){
      #pragma unroll
      for (int w=1;w<4;w++)
        if (wv[w] < v || (wv[w] == v && wi[w] < i)){ v = wv[w]; i = wi[w]; }
      win_sh = i;
      gidx[(size_t)blk*CK + k] = i;
    }
    __syncthreads();
    const int win = win_sh;
    if ((win & 255) == t){
      const int jw = win >> 8;
      #pragma unroll
      for (int j=0;j<32;j++) if (j == jw) dv[j] = 1e30f;
      mv = 1e30f; mi = 0;
      #pragma unroll
      for (int j=0;j<32;j++){
        const int i2 = t + 256*j;
        if (dv[j] < mv || (dv[j] == mv && i2 < mi)){ mv = dv[j]; mi = i2; }
      }
    }
  }
}

// ---------------------------------------------------------------- new_xyz out
__global__ __launch_bounds__(256)
void newxyz_kernel(const float* __restrict__ xyz, const int* __restrict__ fps_idx,
                   float* __restrict__ out0)
{
  const int idx = blockIdx.x*256 + threadIdx.x;
  if (idx >= CB*3*CS) return;
  const int s = idx & 511;
  const int c = (idx >> 9) % 3;
  const int b = idx / (3*CS);
  const int n = fps_idx[b*CS + s];
  out0[idx] = xyz[(size_t)b*3*CN + (size_t)c*CN + n];
}

// ---------------------------------------------------------------- feature transpose [B,D,N] -> [B,N,D]
__global__ __launch_bounds__(256)
void transpose_kernel(const float* __restrict__ f, float* __restrict__ ft)
{
  __shared__ float tile[32][33];
  const int b = blockIdx.z, d0 = blockIdx.y*32, n0 = blockIdx.x*32;
  const int tx = threadIdx.x, ty = threadIdx.y;
  const float* fb = f + (size_t)b*CD*CN;
  #pragma unroll
  for (int r=0;r<32;r+=8) tile[ty+r][tx] = fb[(size_t)(d0+ty+r)*CN + n0+tx];
  __syncthreads();
  float* ftb = ft + (size_t)b*CN*CD;
  #pragma unroll
  for (int r=0;r<32;r+=8) ftb[(size_t)(n0+ty+r)*CD + d0+tx] = tile[tx][ty+r];
}

// ---------------------------------------------------------------- gather + positional encoding + add
__global__ __launch_bounds__(256)
void pe_kernel(const float* __restrict__ xyz, const float* __restrict__ features,
               const float* __restrict__ featT, const int* __restrict__ gidx,
               const float* __restrict__ pe_w1, const float* __restrict__ pe_b1,
               const float* __restrict__ bn_g, const float* __restrict__ bn_b,
               const float* __restrict__ bn_m, const float* __restrict__ bn_v,
               const float* __restrict__ pe_w2, const float* __restrict__ pe_b2,
               float* __restrict__ xout)
{
  __shared__ __align__(16) float w2s[CD*68];
  __shared__ __align__(16) float hr[CK*68];
  __shared__ int idxs[CK];
  __shared__ float gx[CK], gy[CK], gz[CK];
  const int g = blockIdx.x, t = threadIdx.x;
  const int b = g >> 9;
  for (int i=t; i<CD*64; i+=256) w2s[(i>>6)*68 + (i&63)] = pe_w2[i];
  if (t < CK){
    const int id = gidx[(size_t)g*CK + t];
    idxs[t] = id;
    const float* xb = xyz + (size_t)b*3*CN;
    gx[t] = xb[id]; gy[t] = xb[CN+id]; gz[t] = xb[2*CN+id];
  }
  __syncthreads();
  for (int v=t; v<CK*64; v+=256){
    const int k = v>>6, j = v&63;
    float h = ((gx[k]*pe_w1[j*3] + gy[k]*pe_w1[j*3+1]) + gz[k]*pe_w1[j*3+2]) + pe_b1[j];
    h = (h - bn_m[j]) / sqrtf(bn_v[j] + CEPS) * bn_g[j] + bn_b[j];
    hr[k*68+j] = fmaxf(h, 0.f);
  }
  __syncthreads();
  const float* fb  = features + (size_t)b*CD*CN;
  const float* ftb = featT ? (featT + (size_t)b*CN*CD) : nullptr;
  for (int p=t; p<CK*CD; p+=256){
    const int k = p>>7, d = p&127;
    const float4* hp = (const float4*)(hr  + k*68);
    const float4* wp = (const float4*)(w2s + d*68);
    float acc = 0.f;
    #pragma unroll
    for (int j=0;j<16;j++){
      const float4 a = hp[j], w = wp[j];
      acc += a.x*w.x; acc += a.y*w.y; acc += a.z*w.z; acc += a.w*w.w;
    }
    acc += pe_b2[d];
    const float gf = ftb ? ftb[(size_t)idxs[k]*CD + d] : fb[(size_t)d*CN + idxs[k]];
    xout[(size_t)g*CK*CD + p] = gf + acc;
  }
}

// ---------------------------------------------------------------- one transformer layer (per-group block)
__global__ __launch_bounds__(256)
void layer_kernel(float* __restrict__ xbuf,
                  const float* __restrict__ wqkv, const float* __restrict__ bqkv,
                  const float* __restrict__ wo,   const float* __restrict__ bo,
                  const float* __restrict__ g1,   const float* __restrict__ b1v,
                  const float* __restrict__ w1,   const float* __restrict__ bf1,
                  const float* __restrict__ w2,   const float* __restrict__ bf2,
                  const float* __restrict__ g2,   const float* __restrict__ b2v)
{
  __shared__ __align__(16) float xs[CK][CD];        // 16 KB
  __shared__ __align__(16) float qkv[CK][3*CD];     // 48 KB (regions reused)
  const int g = blockIdx.x, t = threadIdx.x;
  float* xg = xbuf + (size_t)g*CK*CD;
  for (int p=t; p<CK*CD; p+=256) (&xs[0][0])[p] = xg[p];
  __syncthreads();

  // ---- QKV projection: 384 outputs x 2 k-halves = 768 tasks, 3 per thread
  for (int r=0;r<3;r++){
    const int tau = t + 256*r;
    const int o = tau >> 1, k0 = (tau & 1)*16;
    const float* wr = wqkv + (size_t)o*CD;
    const float bias = bqkv[o];
    float acc[16];
    #pragma unroll
    for (int k=0;k<16;k++) acc[k]=0.f;
    for (int i=0;i<CD;i+=4){
      const float4 w4 = *(const float4*)(wr+i);
      #pragma unroll
      for (int k=0;k<16;k++){
        const float4 x4 = *(const float4*)(&xs[k0+k][i]);
        acc[k] += x4.x*w4.x; acc[k] += x4.y*w4.y; acc[k] += x4.z*w4.z; acc[k] += x4.w*w4.w;
      }
    }
    #pragma unroll
    for (int k=0;k<16;k++) qkv[k0+k][o] = acc[k] + bias;
  }
  __syncthreads();

  // ---- attention: thread = (head, q)
  {
    const int head = t >> 5, qi = t & 31;
    const float* qr = &qkv[qi][head*CHD];
    float qreg[CHD];
    #pragma unroll
    for (int i=0;i<CHD;i++) qreg[i] = qr[i];
    float sc[CK]; float mx = -1e30f;
    #pragma unroll
    for (int kk=0;kk<CK;kk++){
      const float* kr = &qkv[kk][CD + head*CHD];
      float a = 0.f;
      #pragma unroll
      for (int i=0;i<CHD;i++) a += qreg[i]*kr[i];
      a *= 0.25f;                       // 1/sqrt(16)
      sc[kk] = a; mx = fmaxf(mx, a);
    }
    float ssum = 0.f;
    #pragma unroll
    for (int kk=0;kk<CK;kk++){ const float e = expf(sc[kk]-mx); sc[kk]=e; ssum += e; }
    const float inv = 1.f/ssum;
    float ovv[CHD];
    #pragma unroll
    for (int i=0;i<CHD;i++) ovv[i]=0.f;
    #pragma unroll
    for (int kk=0;kk<CK;kk++){
      const float pw = sc[kk]*inv;
      const float* vr = &qkv[kk][2*CD + head*CHD];
      #pragma unroll
      for (int i=0;i<CHD;i++) ovv[i] += pw*vr[i];
    }
    __syncthreads();                   // all q/k/v reads done
    #pragma unroll
    for (int i=0;i<CHD;i++) qkv[qi][head*CHD+i] = ovv[i];   // q-region := attn out
  }
  __syncthreads();

  // ---- O-proj + residual -> y in cols [CD,2CD)
  {
    const int d = t >> 1, k0 = (t & 1)*16;
    const float* wr = wo + (size_t)d*CD;
    const float bias = bo[d];
    float acc[16];
    #pragma unroll
    for (int k=0;k<16;k++) acc[k]=0.f;
    for (int i=0;i<CD;i+=4){
      const float4 w4 = *(const float4*)(wr+i);
      #pragma unroll
      for (int k=0;k<16;k++){
        const float4 x4 = *(const float4*)(&qkv[k0+k][i]);
        acc[k] += x4.x*w4.x; acc[k] += x4.y*w4.y; acc[k] += x4.z*w4.z; acc[k] += x4.w*w4.w;
      }
    }
    #pragma unroll
    for (int k=0;k<16;k++) qkv[k0+k][CD+d] = xs[k0+k][d] + (acc[k] + bias);
  }
  __syncthreads();

  // ---- LN1 -> xs   (8 lanes per token)
  {
    const int k = t >> 3, l = t & 7;
    float s0 = 0.f;
    #pragma unroll
    for (int j=0;j<16;j++) s0 += qkv[k][CD + l + 8*j];
    #pragma unroll
    for (int off=1; off<8; off<<=1) s0 += __shfl_xor(s0, off);
    const float mean = s0 * (1.f/CD);
    float v0 = 0.f;
    #pragma unroll
    for (int j=0;j<16;j++){ const float dd = qkv[k][CD + l + 8*j] - mean; v0 += dd*dd; }
    #pragma unroll
    for (int off=1; off<8; off<<=1) v0 += __shfl_xor(v0, off);
    const float inv = 1.f/sqrtf(v0*(1.f/CD) + CEPS);
    #pragma unroll
    for (int j=0;j<16;j++){
      const int d = l + 8*j;
      xs[k][d] = (qkv[k][CD+d] - mean)*inv*g1[d] + b1v[d];
    }
  }
  __syncthreads();

  // ---- FFN1 (relu) -> h1 in cols [0,2CD) ; 256 outputs x 2 halves = 2 tasks/thread
  for (int r=0;r<2;r++){
    const int tau = t + 256*r;
    const int f = tau >> 1, k0 = (tau & 1)*16;
    const float* wr = w1 + (size_t)f*CD;
    const float bias = bf1[f];
    float acc[16];
    #pragma unroll
    for (int k=0;k<16;k++) acc[k]=0.f;
    for (int i=0;i<CD;i+=4){
      const float4 w4 = *(const float4*)(wr+i);
      #pragma unroll
      for (int k=0;k<16;k++){
        const float4 x4 = *(const float4*)(&xs[k0+k][i]);
        acc[k] += x4.x*w4.x; acc[k] += x4.y*w4.y; acc[k] += x4.z*w4.z; acc[k] += x4.w*w4.w;
      }
    }
    #pragma unroll
    for (int k=0;k<16;k++) qkv[k0+k][f] = fmaxf(acc[k] + bias, 0.f);
  }
  __syncthreads();

  // ---- FFN2 + residual -> y2 in cols [2CD,3CD)
  {
    const int d = t >> 1, k0 = (t & 1)*16;
    const float* wr = w2 + (size_t)d*CF;
    const float bias = bf2[d];
    float acc[16];
    #pragma unroll
    for (int k=0;k<16;k++) acc[k]=0.f;
    for (int f=0; f<CF; f+=4){
      const float4 w4 = *(const float4*)(wr+f);
      #pragma unroll
      for (int k=0;k<16;k++){
        const float4 h4 = *(const float4*)(&qkv[k0+k][f]);
        acc[k] += h4.x*w4.x; acc[k] += h4.y*w4.y; acc[k] += h4.z*w4.z; acc[k] += h4.w*w4.w;
      }
    }
    #pragma unroll
    for (int k=0;k<16;k++) qkv[k0+k][2*CD+d] = xs[k0+k][d] + (acc[k] + bias);
  }
  __syncthreads();

  // ---- LN2 -> xs -> global
  {
    const int k = t >> 3, l = t & 7;
    float s0 = 0.f;
    #pragma unroll
    for (int j=0;j<16;j++) s0 += qkv[k][2*CD + l + 8*j];
    #pragma unroll
    for (int off=1; off<8; off<<=1) s0 += __shfl_xor(s0, off);
    const float mean = s0 * (1.f/CD);
    float v0 = 0.f;
    #pragma unroll
    for (int j=0;j<16;j++){ const float dd = qkv[k][2*CD + l + 8*j] - mean; v0 += dd*dd; }
    #pragma unroll
    for (int off=1; off<8; off<<=1) v0 += __shfl_xor(v0, off);
    const float inv = 1.f/sqrtf(v0*(1.f/CD) + CEPS);
    #pragma unroll
    for (int j=0;j<16;j++){
      const int d = l + 8*j;
      xs[k][d] = (qkv[k][2*CD+d] - mean)*inv*g2[d] + b2v[d];
    }
  }
  __syncthreads();
  for (int p=t; p<CK*CD; p+=256) xg[p] = (&xs[0][0])[p];
}

// ---------------------------------------------------------------- max-pool + fc
__global__ __launch_bounds__(256)
void poolfc_kernel(const float* __restrict__ xbuf, const float* __restrict__ fc_w,
                   const float* __restrict__ fc_b, float* __restrict__ fcout)
{
  __shared__ __align__(16) float pooled[CD];
  const int gg = blockIdx.x, t = threadIdx.x;
  const float* xg = xbuf + (size_t)gg*CK*CD;
  if (t < CD){
    float m = -1e30f;
    for (int k=0;k<CK;k++) m = fmaxf(m, xg[(size_t)k*CD + t]);
    pooled[t] = m;
  }
  __syncthreads();
  const float* wr = fc_w + (size_t)t*CD;
  float acc = 0.f;
  const float4* pp = (const float4*)pooled;
  for (int i=0;i<CD/4;i++){
    const float4 w4 = *(const float4*)(wr + 4*i);
    const float4 p4 = pp[i];
    acc += p4.x*w4.x; acc += p4.y*w4.y; acc += p4.z*w4.z; acc += p4.w*w4.w;
  }
  acc += fc_b[t];
  const int b = gg >> 9, s = gg & 511;
  fcout[((size_t)b*CS + s)*CO + t] = acc;   // layout [B,S,O]
}

// ---------------------------------------------------------------- linear interp S -> N
__global__ __launch_bounds__(256)
void interp_kernel(const float* __restrict__ fcout, float* __restrict__ out1)
{
  const int idx = blockIdx.x*256 + threadIdx.x;
  const int n  = idx & (CN-1);
  const int bo = idx >> 13;
  const int b  = bo >> 8, o = bo & 255;
  const double pos = (double)n * ((double)(CS-1)/(double)(CN-1));
  const int i0 = (int)pos;                 // floor (pos >= 0)
  const int i1 = min(i0+1, CS-1);
  const float w = (float)(pos - (double)i0);
  const float v0 = fcout[((size_t)b*CS + i0)*CO + o];
  const float v1 = fcout[((size_t)b*CS + i1)*CO + o];
  out1[idx] = v0*(1.f - w) + v1*w;
}

// ---------------------------------------------------------------- launcher
extern "C" void kernel_launch(void* const* d_in, const int* in_sizes, int n_in,
                              void* d_out, int out_size, void* d_ws, size_t ws_size,
                              hipStream_t stream)
{
  (void)in_sizes; (void)n_in; (void)out_size;
  const float* xyz      = (const float*)d_in[0];
  const float* features = (const float*)d_in[1];
  const float* pe_w1    = (const float*)d_in[2];
  const float* pe_b1    = (const float*)d_in[3];
  const float* bn_g     = (const float*)d_in[4];
  const float* bn_b     = (const float*)d_in[5];
  const float* bn_m     = (const float*)d_in[6];
  const float* bn_v     = (const float*)d_in[7];
  const float* pe_w2    = (const float*)d_in[8];
  const float* pe_b2    = (const float*)d_in[9];
  const float* wqkv     = (const float*)d_in[10];
  const float* bqkv     = (const float*)d_in[11];
  const float* wo       = (const float*)d_in[12];
  const float* bo       = (const float*)d_in[13];
  const float* g1       = (const float*)d_in[14];
  const float* b1       = (const float*)d_in[15];
  const float* w1       = (const float*)d_in[16];
  const float* bf1      = (const float*)d_in[17];
  const float* w2       = (const float*)d_in[18];
  const float* bf2      = (const float*)d_in[19];
  const float* g2       = (const float*)d_in[20];
  const float* b2       = (const float*)d_in[21];
  const float* fc_w     = (const float*)d_in[22];
  const float* fc_b     = (const float*)d_in[23];

  char* ws = (char*)d_ws;
  int*   fps_idx = (int*)(ws);                                    // 16 KB
  int*   gidx    = (int*)(ws + 65536);                            // 512 KB
  float* xbuf    = (float*)(ws + (1u<<20));                       // 64 MB
  float* fcout   = (float*)(ws + (1u<<20) + ((size_t)64<<20));    // 4 MB
  float* featT   = (float*)(ws + ((size_t)72<<20));               // 32 MB
  const bool useT = ws_size >= ((size_t)106<<20);

  float* out0 = (float*)d_out;
  float* out1 = out0 + CB*3*CS;

  fps_kernel<<<CB, 1024, 0, stream>>>(xyz, fps_idx);
  knn_kernel<<<CB*CS, 256, 0, stream>>>(xyz, fps_idx, gidx);
  newxyz_kernel<<<(CB*3*CS + 255)/256, 256, 0, stream>>>(xyz, fps_idx, out0);
  if (useT){
    dim3 tb(32, 8), tg(CN/32, CD/32, CB);
    transpose_kernel<<<tg, tb, 0, stream>>>(features, featT);
  }
  pe_kernel<<<CB*CS, 256, 0, stream>>>(xyz, features, useT ? featT : nullptr, gidx,
                                       pe_w1, pe_b1, bn_g, bn_b, bn_m, bn_v,
                                       pe_w2, pe_b2, xbuf);
  for (int L=0; L<4; L++){
    layer_kernel<<<CB*CS, 256, 0, stream>>>(xbuf,
        wqkv + (size_t)L*3*CD*CD, bqkv + (size_t)L*3*CD,
        wo   + (size_t)L*CD*CD,   bo   + (size_t)L*CD,
        g1   + (size_t)L*CD,      b1   + (size_t)L*CD,
        w1   + (size_t)L*CF*CD,   bf1  + (size_t)L*CF,
        w2   + (size_t)L*CD*CF,   bf2  + (size_t)L*CD,
        g2   + (size_t)L*CD,      b2   + (size_t)L*CD);
  }
  poolfc_kernel<<<CB*CS, 256, 0, stream>>>(xbuf, fc_w, fc_b, fcout);
  interp_kernel<<<(CB*CO*CN)/256, 256, 0, stream>>>(fcout, out1);
}

// Round 2
// 1817.190 us; speedup vs baseline: 3.0728x; 3.0728x over previous
//
#include <hip/hip_runtime.h>
#include <math.h>

constexpr int CB  = 8;     // batches
constexpr int CN  = 8192;  // points
constexpr int CS  = 512;   // npoint
constexpr int CK  = 32;    // nsample
constexpr int CD  = 128;   // dim
constexpr int CF  = 256;   // dff
constexpr int CO  = 256;   // dim_out
constexpr float CEPS = 1e-5f;

typedef __attribute__((ext_vector_type(8)))  short short8;
typedef __attribute__((ext_vector_type(4)))  float f32x4;
typedef __attribute__((ext_vector_type(16))) float f32x16;
#define MFMA16(a,b,c) __builtin_amdgcn_mfma_f32_16x16x32_bf16(a,b,c,0,0,0)
#define MFMA32(a,b,c) __builtin_amdgcn_mfma_f32_32x32x16_bf16(a,b,c,0,0,0)

__device__ __forceinline__ ushort f2b(float f){
  unsigned u = __builtin_bit_cast(unsigned, f);
  u = u + 0x7fffu + ((u >> 16) & 1u);
  return (ushort)(u >> 16);
}

// ---------------------------------------------------------------- FPS
__global__ __launch_bounds__(1024)
void fps_kernel(const float* __restrict__ xyz, int* __restrict__ fps_idx)
{
#pragma clang fp contract(off)
  __shared__ float4 p4[CN];            // 128 KB
  __shared__ float wbest[16];
  __shared__ int   widx[16];
  __shared__ int   far_sh;
  const int b = blockIdx.x, t = threadIdx.x;
  const float* xb = xyz + (size_t)b*3*CN;
  for (int i = t; i < CN; i += 1024)
    p4[i] = make_float4(xb[i], xb[CN+i], xb[2*CN+i], 0.f);
  float dist[8];
  #pragma unroll
  for (int j=0;j<8;j++) dist[j] = 1e10f;
  __syncthreads();
  int far = 0;
  for (int it = 0; it < CS; ++it){
    if (t == 0) fps_idx[b*CS + it] = far;
    const float4 c = p4[far];
    float best = -1.f; int bi = 0;
    #pragma unroll
    for (int j=0;j<8;j++){
      const int i = t + 1024*j;
      const float4 p = p4[i];
      const float dx = p.x - c.x, dy = p.y - c.y, dz = p.z - c.z;
      const float d2 = (dx*dx + dy*dy) + dz*dz;
      const float nd = fminf(dist[j], d2);
      dist[j] = nd;
      if (nd > best){ best = nd; bi = i; }
    }
    #pragma unroll
    for (int off=32; off>=1; off>>=1){
      const float ob = __shfl_xor(best, off);
      const int   oi = __shfl_xor(bi, off);
      if (ob > best || (ob == best && oi < bi)){ best = ob; bi = oi; }
    }
    if ((t & 63) == 0){ wbest[t>>6] = best; widx[t>>6] = bi; }
    __syncthreads();
    if (t < 16){
      best = wbest[t]; bi = widx[t];
      #pragma unroll
      for (int off=8; off>=1; off>>=1){
        const float ob = __shfl_xor(best, off);
        const int   oi = __shfl_xor(bi, off);
        if (ob > best || (ob == best && oi < bi)){ best = ob; bi = oi; }
      }
      if (t == 0) far_sh = bi;
    }
    __syncthreads();
    far = far_sh;
  }
}

// ---------------------------------------------------------------- kNN top-32
__global__ __launch_bounds__(256)
void knn_kernel(const float* __restrict__ xyz, const int* __restrict__ fps_idx,
                int* __restrict__ gidx)
{
#pragma clang fp contract(off)
  __shared__ float wv[4];
  __shared__ int   wi[4];
  __shared__ int   win_sh;
  const int blk = blockIdx.x, t = threadIdx.x;
  const int b = blk >> 9;
  const int s = blk & 511;
  const float* xb = xyz + (size_t)b*3*CN;
  const int cidx = fps_idx[b*CS + s];
  const float cx = xb[cidx], cy = xb[CN+cidx], cz = xb[2*CN+cidx];
  const float cn2 = (cx*cx + cy*cy) + cz*cz;
  float dv[32];
  float mv = 1e30f; int mi = 0;
  #pragma unroll
  for (int j=0;j<32;j++){
    const int i = t + 256*j;
    const float x = xb[i], y = xb[CN+i], z = xb[2*CN+i];
    const float pn2 = (x*x + y*y) + z*z;
    const float dot = (cx*x + cy*y) + cz*z;
    const float d2 = (cn2 + pn2) - 2.0f*dot;
    dv[j] = d2;
    if (d2 < mv || (d2 == mv && i < mi)){ mv = d2; mi = i; }
  }
  for (int k=0;k<CK;k++){
    float v = mv; int i = mi;
    #pragma unroll
    for (int off=32; off>=1; off>>=1){
      const float ov = __shfl_xor(v, off);
      const int   oi = __shfl_xor(i, off);
      if (ov < v || (ov == v && oi < i)){ v = ov; i = oi; }
    }
    if ((t & 63) == 0){ wv[t>>6] = v; wi[t>>6] = i; }
    __syncthreads();
    if (t == 0){
      #pragma unroll
      for (int w=1;w<4;w++)
        if (wv[w] < v || (wv[w] == v && wi[w] < i)){ v = wv[w]; i = wi[w]; }
      win_sh = i;
      gidx[(size_t)blk*CK + k] = i;
    }
    __syncthreads();
    const int win = win_sh;
    if ((win & 255) == t){
      const int jw = win >> 8;
      #pragma unroll
      for (int j=0;j<32;j++) if (j == jw) dv[j] = 1e30f;
      mv = 1e30f; mi = 0;
      #pragma unroll
      for (int j=0;j<32;j++){
        const int i2 = t + 256*j;
        if (dv[j] < mv || (dv[j] == mv && i2 < mi)){ mv = dv[j]; mi = i2; }
      }
    }
  }
}

// ---------------------------------------------------------------- new_xyz out
__global__ __launch_bounds__(256)
void newxyz_kernel(const float* __restrict__ xyz, const int* __restrict__ fps_idx,
                   float* __restrict__ out0)
{
  const int idx = blockIdx.x*256 + threadIdx.x;
  if (idx >= CB*3*CS) return;
  const int s = idx & 511;
  const int c = (idx >> 9) % 3;
  const int b = idx / (3*CS);
  const int n = fps_idx[b*CS + s];
  out0[idx] = xyz[(size_t)b*3*CN + (size_t)c*CN + n];
}

// ---------------------------------------------------------------- feature transpose [B,D,N] -> [B,N,D]
__global__ __launch_bounds__(256)
void transpose_kernel(const float* __restrict__ f, float* __restrict__ ft)
{
  __shared__ float tile[32][33];
  const int b = blockIdx.z, d0 = blockIdx.y*32, n0 = blockIdx.x*32;
  const int tx = threadIdx.x, ty = threadIdx.y;
  const float* fb = f + (size_t)b*CD*CN;
  #pragma unroll
  for (int r=0;r<32;r+=8) tile[ty+r][tx] = fb[(size_t)(d0+ty+r)*CN + n0+tx];
  __syncthreads();
  float* ftb = ft + (size_t)b*CN*CD;
  #pragma unroll
  for (int r=0;r<32;r+=8) ftb[(size_t)(n0+ty+r)*CD + d0+tx] = tile[tx][ty+r];
}

// ---------------------------------------------------------------- gather + positional encoding + add
__global__ __launch_bounds__(256)
void pe_kernel(const float* __restrict__ xyz, const float* __restrict__ features,
               const float* __restrict__ featT, const int* __restrict__ gidx,
               const float* __restrict__ pe_w1, const float* __restrict__ pe_b1,
               const float* __restrict__ bn_g, const float* __restrict__ bn_b,
               const float* __restrict__ bn_m, const float* __restrict__ bn_v,
               const float* __restrict__ pe_w2, const float* __restrict__ pe_b2,
               float* __restrict__ xout)
{
  __shared__ __align__(16) float w2s[CD*68];
  __shared__ __align__(16) float hr[CK*68];
  __shared__ int idxs[CK];
  __shared__ float gx[CK], gy[CK], gz[CK];
  const int g = blockIdx.x, t = threadIdx.x;
  const int b = g >> 9;
  for (int i=t; i<CD*64; i+=256) w2s[(i>>6)*68 + (i&63)] = pe_w2[i];
  if (t < CK){
    const int id = gidx[(size_t)g*CK + t];
    idxs[t] = id;
    const float* xb = xyz + (size_t)b*3*CN;
    gx[t] = xb[id]; gy[t] = xb[CN+id]; gz[t] = xb[2*CN+id];
  }
  __syncthreads();
  for (int v=t; v<CK*64; v+=256){
    const int k = v>>6, j = v&63;
    float h = ((gx[k]*pe_w1[j*3] + gy[k]*pe_w1[j*3+1]) + gz[k]*pe_w1[j*3+2]) + pe_b1[j];
    h = (h - bn_m[j]) / sqrtf(bn_v[j] + CEPS) * bn_g[j] + bn_b[j];
    hr[k*68+j] = fmaxf(h, 0.f);
  }
  __syncthreads();
  const float* fb  = features + (size_t)b*CD*CN;
  const float* ftb = featT ? (featT + (size_t)b*CN*CD) : nullptr;
  for (int p=t; p<CK*CD; p+=256){
    const int k = p>>7, d = p&127;
    const float4* hp = (const float4*)(hr  + k*68);
    const float4* wp = (const float4*)(w2s + d*68);
    float acc = 0.f;
    #pragma unroll
    for (int j=0;j<16;j++){
      const float4 a = hp[j], w = wp[j];
      acc += a.x*w.x; acc += a.y*w.y; acc += a.z*w.z; acc += a.w*w.w;
    }
    acc += pe_b2[d];
    const float gf = ftb ? ftb[(size_t)idxs[k]*CD + d] : fb[(size_t)d*CN + idxs[k]];
    xout[(size_t)g*CK*CD + p] = gf + acc;
  }
}

// ---------------------------------------------------------------- weight prep -> bf16 MFMA B-fragments
// per layer (256 frags x 64 lanes x 8 bf16 = 131072 bf16):
//   fid 0..95   : wqkv  nt=fid>>2 (24), kt=fid&3 (4)
//   fid 96..127 : wo    nt (8), kt (4)
//   fid 128..191: w1    nt (16), kt (4)
//   fid 192..255: w2    nt (8), kt 0..7 (K=256)
// lane l supplies B[k=kt*32+(l>>4)*8+j][n=nt*16+(l&15)] = W[n][k..k+7]
__global__ __launch_bounds__(256)
void wprep_kernel(const float* __restrict__ wqkv, const float* __restrict__ wo,
                  const float* __restrict__ w1,   const float* __restrict__ w2,
                  ushort* __restrict__ dst)
{
  const int tid = blockIdx.x*256 + threadIdx.x;   // 65536 threads
  const int l = tid & 63;
  const int f = tid >> 6;          // 0..1023
  const int L = f >> 8;
  const int r = f & 255;
  const float* src; int stride, nt, kt;
  if (r < 96)      { nt = r>>2;        kt = r&3;        src = wqkv + (size_t)L*384*128; stride = 128; }
  else if (r < 128){ nt = (r-96)>>2;   kt = (r-96)&3;   src = wo   + (size_t)L*128*128; stride = 128; }
  else if (r < 192){ nt = (r-128)>>2;  kt = (r-128)&3;  src = w1   + (size_t)L*256*128; stride = 128; }
  else             { nt = (r-192)>>3;  kt = (r-192)&7;  src = w2   + (size_t)L*128*256; stride = 256; }
  const int n = nt*16 + (l & 15);
  const int k = kt*32 + (l >> 4)*8;
  const float* p = src + (size_t)n*stride + k;
  uint4 o;
  o.x = (unsigned)f2b(p[0]) | ((unsigned)f2b(p[1])<<16);
  o.y = (unsigned)f2b(p[2]) | ((unsigned)f2b(p[3])<<16);
  o.z = (unsigned)f2b(p[4]) | ((unsigned)f2b(p[5])<<16);
  o.w = (unsigned)f2b(p[6]) | ((unsigned)f2b(p[7])<<16);
  *(uint4*)(dst + (size_t)tid*8) = o;
}

// ---------------------------------------------------------------- fused MFMA transformer layer
// block = 1 group (32 tokens), 256 threads (4 waves). LDS strides padded.
__device__ __forceinline__ void ln_inplace(float* x32s, ushort* xbv,
                                           const float* __restrict__ gamma,
                                           const float* __restrict__ beta, int t)
{
  const int r = t >> 3, j = t & 7;
  float v[16]; float s = 0.f;
  #pragma unroll
  for (int i=0;i<16;i++){ v[i] = x32s[r*132 + j + 8*i]; s += v[i]; }
  #pragma unroll
  for (int off=1; off<8; off<<=1) s += __shfl_xor(s, off);
  const float mean = s * (1.f/128.f);
  float var = 0.f;
  #pragma unroll
  for (int i=0;i<16;i++){ const float d = v[i]-mean; var += d*d; }
  #pragma unroll
  for (int off=1; off<8; off<<=1) var += __shfl_xor(var, off);
  const float inv = 1.f / sqrtf(var*(1.f/128.f) + CEPS);
  #pragma unroll
  for (int i=0;i<16;i++){
    const int d = j + 8*i;
    const float o = (v[i]-mean)*inv*gamma[d] + beta[d];
    x32s[r*132 + d] = o;
    xbv[r*136 + d] = f2b(o);
  }
}

__global__ __launch_bounds__(256, 2)
void layer_mfma_kernel(float* __restrict__ xbuf, const ushort* __restrict__ wf,
                       const float* __restrict__ bqkv, const float* __restrict__ bo,
                       const float* __restrict__ g1, const float* __restrict__ b1v,
                       const float* __restrict__ bf1, const float* __restrict__ bf2,
                       const float* __restrict__ g2, const float* __restrict__ b2v)
{
  __shared__ __align__(16) float  x32s[32*132];   // 16.5 KB fp32 current tensor (residual path)
  __shared__ __align__(16) ushort xbv [32*136];   // 8.5 KB bf16 A-operand buffer
  __shared__ __align__(16) ushort qk  [32*264];   // 16.5 KB bf16: Q cols 0..127, K cols 128..255; later FFN1 out (256)
  __shared__ __align__(16) ushort vT  [128*40];   // 10 KB bf16 V transposed [dim][token]
  __shared__ __align__(16) ushort Pb  [4*32*40];  // 10 KB bf16 per-wave P scratch
  const int g = blockIdx.x, t = threadIdx.x;
  const int w = t>>6, l = t&63;
  const int l15 = l&15, q4 = l>>4, l31 = l&31, hi = l>>5;
  float* xg = xbuf + (size_t)g*1024*4;            // 32*128
  const uint4* wfv = (const uint4*)wf;

  // ---- load x (fp32 + bf16 copies)
  for (int i=t;i<1024;i+=256){
    const float4 v = ((const float4*)xg)[i];
    const int r = i>>5, c = (i&31)*4;
    *(float4*)&x32s[r*132 + c] = v;
    uint2 p;
    p.x = (unsigned)f2b(v.x) | ((unsigned)f2b(v.y)<<16);
    p.y = (unsigned)f2b(v.z) | ((unsigned)f2b(v.w)<<16);
    *(uint2*)&xbv[r*136 + c] = p;
  }
  __syncthreads();

  // ---- QKV: [32x128] x [128x384]
  {
    short8 a[2][4];
    #pragma unroll
    for (int mt=0;mt<2;mt++)
      #pragma unroll
      for (int kt=0;kt<4;kt++)
        a[mt][kt] = __builtin_bit_cast(short8, *(const uint4*)&xbv[(l15+16*mt)*136 + kt*32 + q4*8]);
    for (int i=0;i<6;i++){
      const int nt = w + 4*i;
      const int n  = nt*16 + l15;
      f32x4 a0 = {0.f,0.f,0.f,0.f}, a1 = {0.f,0.f,0.f,0.f};
      #pragma unroll
      for (int kt=0;kt<4;kt++){
        const short8 b = __builtin_bit_cast(short8, wfv[(nt*4+kt)*64 + l]);
        a0 = MFMA16(a[0][kt], b, a0);
        a1 = MFMA16(a[1][kt], b, a1);
      }
      const float bias = bqkv[n];
      if (nt < 16){  // Q,K -> row-major
        #pragma unroll
        for (int i2=0;i2<4;i2++){
          qk[(q4*4+i2   )*264 + n] = f2b(a0[i2]+bias);
          qk[(q4*4+i2+16)*264 + n] = f2b(a1[i2]+bias);
        }
      } else {       // V -> transposed [dim][token]
        const int d = n - 256;
        uint2 p0, p1;
        p0.x = (unsigned)f2b(a0[0]+bias) | ((unsigned)f2b(a0[1]+bias)<<16);
        p0.y = (unsigned)f2b(a0[2]+bias) | ((unsigned)f2b(a0[3]+bias)<<16);
        p1.x = (unsigned)f2b(a1[0]+bias) | ((unsigned)f2b(a1[1]+bias)<<16);
        p1.y = (unsigned)f2b(a1[2]+bias) | ((unsigned)f2b(a1[3]+bias)<<16);
        *(uint2*)&vT[d*40 + q4*4]      = p0;
        *(uint2*)&vT[d*40 + 16 + q4*4] = p1;
      }
    }
  }
  __syncthreads();

  // ---- attention: wave handles heads 2w, 2w+1
  for (int hh=0; hh<2; hh++){
    const int h = 2*w + hh;
    // S^T = K * Q^T  (32x32x16): D[key][q], lane: col q=l31, rows=keys
    const short8 ka = __builtin_bit_cast(short8, *(const uint4*)&qk[l31*264 + 128 + h*16 + hi*8]);
    const short8 qb = __builtin_bit_cast(short8, *(const uint4*)&qk[l31*264 +       h*16 + hi*8]);
    f32x16 s;
    #pragma unroll
    for (int i=0;i<16;i++) s[i] = 0.f;
    s = MFMA32(ka, qb, s);
    float e[16]; float mx = -1e30f;
    #pragma unroll
    for (int i=0;i<16;i++){ e[i] = s[i]*0.25f; mx = fmaxf(mx, e[i]); }
    mx = fmaxf(mx, __shfl_xor(mx, 32));
    float sum = 0.f;
    #pragma unroll
    for (int i=0;i<16;i++){ e[i] = __expf(e[i]-mx); sum += e[i]; }
    sum += __shfl_xor(sum, 32);
    const float inv = 1.f/sum;
    // write P[q][key] bf16 ; reg 4j+i <-> key 8j+4hi+i
    #pragma unroll
    for (int j=0;j<4;j++){
      uint2 p;
      p.x = (unsigned)f2b(e[4*j  ]*inv) | ((unsigned)f2b(e[4*j+1]*inv)<<16);
      p.y = (unsigned)f2b(e[4*j+2]*inv) | ((unsigned)f2b(e[4*j+3]*inv)<<16);
      *(uint2*)&Pb[w*1280 + l31*40 + j*8 + hi*4] = p;
    }
    // O = P * V  (16x16x32): B[k=key][n=d] from vT rows
    const short8 bv = __builtin_bit_cast(short8, *(const uint4*)&vT[(h*16+l15)*40 + q4*8]);
    #pragma unroll
    for (int mt=0;mt<2;mt++){
      const short8 ap = __builtin_bit_cast(short8, *(const uint4*)&Pb[w*1280 + (l15+16*mt)*40 + q4*8]);
      f32x4 o = {0.f,0.f,0.f,0.f};
      o = MFMA16(ap, bv, o);
      #pragma unroll
      for (int i2=0;i2<4;i2++)
        xbv[(16*mt + q4*4 + i2)*136 + h*16 + l15] = f2b(o[i2]);  // attn_out overwrites x_bf16
    }
  }
  __syncthreads();

  // ---- O-proj + residual (in-place fp32)
  {
    short8 a[2][4];
    #pragma unroll
    for (int mt=0;mt<2;mt++)
      #pragma unroll
      for (int kt=0;kt<4;kt++)
        a[mt][kt] = __builtin_bit_cast(short8, *(const uint4*)&xbv[(l15+16*mt)*136 + kt*32 + q4*8]);
    for (int i=0;i<2;i++){
      const int nt = w + 4*i;
      const int n  = nt*16 + l15;
      f32x4 a0 = {0.f,0.f,0.f,0.f}, a1 = {0.f,0.f,0.f,0.f};
      #pragma unroll
      for (int kt=0;kt<4;kt++){
        const short8 b = __builtin_bit_cast(short8, wfv[(96 + nt*4+kt)*64 + l]);
        a0 = MFMA16(a[0][kt], b, a0);
        a1 = MFMA16(a[1][kt], b, a1);
      }
      const float bias = bo[n];
      #pragma unroll
      for (int i2=0;i2<4;i2++){
        x32s[(q4*4+i2   )*132 + n] += a0[i2] + bias;
        x32s[(q4*4+i2+16)*132 + n] += a1[i2] + bias;
      }
    }
  }
  __syncthreads();
  ln_inplace(x32s, xbv, g1, b1v, t);   // x32s := LN1 (fp32), xbv := LN1 (bf16)
  __syncthreads();

  // ---- FFN1 + relu -> qk (h1, 256 cols)
  {
    short8 a[2][4];
    #pragma unroll
    for (int mt=0;mt<2;mt++)
      #pragma unroll
      for (int kt=0;kt<4;kt++)
        a[mt][kt] = __builtin_bit_cast(short8, *(const uint4*)&xbv[(l15+16*mt)*136 + kt*32 + q4*8]);
    for (int i=0;i<4;i++){
      const int nt = w + 4*i;
      const int n  = nt*16 + l15;
      f32x4 a0 = {0.f,0.f,0.f,0.f}, a1 = {0.f,0.f,0.f,0.f};
      #pragma unroll
      for (int kt=0;kt<4;kt++){
        const short8 b = __builtin_bit_cast(short8, wfv[(128 + nt*4+kt)*64 + l]);
        a0 = MFMA16(a[0][kt], b, a0);
        a1 = MFMA16(a[1][kt], b, a1);
      }
      const float bias = bf1[n];
      #pragma unroll
      for (int i2=0;i2<4;i2++){
        qk[(q4*4+i2   )*264 + n] = f2b(fmaxf(a0[i2]+bias, 0.f));
        qk[(q4*4+i2+16)*264 + n] = f2b(fmaxf(a1[i2]+bias, 0.f));
      }
    }
  }
  __syncthreads();

  // ---- FFN2 + residual (in-place fp32), K=256
  {
    short8 a[2][8];
    #pragma unroll
    for (int mt=0;mt<2;mt++)
      #pragma unroll
      for (int kt=0;kt<8;kt++)
        a[mt][kt] = __builtin_bit_cast(short8, *(const uint4*)&qk[(l15+16*mt)*264 + kt*32 + q4*8]);
    for (int i=0;i<2;i++){
      const int nt = w + 4*i;
      const int n  = nt*16 + l15;
      f32x4 a0 = {0.f,0.f,0.f,0.f}, a1 = {0.f,0.f,0.f,0.f};
      #pragma unroll
      for (int kt=0;kt<8;kt++){
        const short8 b = __builtin_bit_cast(short8, wfv[(192 + nt*8+kt)*64 + l]);
        a0 = MFMA16(a[0][kt], b, a0);
        a1 = MFMA16(a[1][kt], b, a1);
      }
      const float bias = bf2[n];
      #pragma unroll
      for (int i2=0;i2<4;i2++){
        x32s[(q4*4+i2   )*132 + n] += a0[i2] + bias;
        x32s[(q4*4+i2+16)*132 + n] += a1[i2] + bias;
      }
    }
  }
  __syncthreads();
  ln_inplace(x32s, xbv, g2, b2v, t);
  __syncthreads();

  // ---- store x
  for (int i=t;i<1024;i+=256){
    const int r = i>>5, c = (i&31)*4;
    ((float4*)xg)[i] = *(const float4*)&x32s[r*132 + c];
  }
}

// ---------------------------------------------------------------- max-pool + fc
__global__ __launch_bounds__(256)
void poolfc_kernel(const float* __restrict__ xbuf, const float* __restrict__ fc_w,
                   const float* __restrict__ fc_b, float* __restrict__ fcout)
{
  __shared__ __align__(16) float pooled[CD];
  const int gg = blockIdx.x, t = threadIdx.x;
  const float* xg = xbuf + (size_t)gg*CK*CD;
  if (t < CD){
    float m = -1e30f;
    for (int k=0;k<CK;k++) m = fmaxf(m, xg[(size_t)k*CD + t]);
    pooled[t] = m;
  }
  __syncthreads();
  const float* wr = fc_w + (size_t)t*CD;
  float acc = 0.f;
  const float4* pp = (const float4*)pooled;
  for (int i=0;i<CD/4;i++){
    const float4 w4 = *(const float4*)(wr + 4*i);
    const float4 p4 = pp[i];
    acc += p4.x*w4.x; acc += p4.y*w4.y; acc += p4.z*w4.z; acc += p4.w*w4.w;
  }
  acc += fc_b[t];
  const int b = gg >> 9, s = gg & 511;
  fcout[((size_t)b*CS + s)*CO + t] = acc;   // layout [B,S,O]
}

// ---------------------------------------------------------------- linear interp S -> N
__global__ __launch_bounds__(256)
void interp_kernel(const float* __restrict__ fcout, float* __restrict__ out1)
{
  const int idx = blockIdx.x*256 + threadIdx.x;
  const int n  = idx & (CN-1);
  const int bo = idx >> 13;
  const int b  = bo >> 8, o = bo & 255;
  const double pos = (double)n * ((double)(CS-1)/(double)(CN-1));
  const int i0 = (int)pos;
  const int i1 = min(i0+1, CS-1);
  const float w = (float)(pos - (double)i0);
  const float v0 = fcout[((size_t)b*CS + i0)*CO + o];
  const float v1 = fcout[((size_t)b*CS + i1)*CO + o];
  out1[idx] = v0*(1.f - w) + v1*w;
}

// ---------------------------------------------------------------- launcher
extern "C" void kernel_launch(void* const* d_in, const int* in_sizes, int n_in,
                              void* d_out, int out_size, void* d_ws, size_t ws_size,
                              hipStream_t stream)
{
  (void)in_sizes; (void)n_in; (void)out_size;
  const float* xyz      = (const float*)d_in[0];
  const float* features = (const float*)d_in[1];
  const float* pe_w1    = (const float*)d_in[2];
  const float* pe_b1    = (const float*)d_in[3];
  const float* bn_g     = (const float*)d_in[4];
  const float* bn_b     = (const float*)d_in[5];
  const float* bn_m     = (const float*)d_in[6];
  const float* bn_v     = (const float*)d_in[7];
  const float* pe_w2    = (const float*)d_in[8];
  const float* pe_b2    = (const float*)d_in[9];
  const float* wqkv     = (const float*)d_in[10];
  const float* bqkv     = (const float*)d_in[11];
  const float* wo       = (const float*)d_in[12];
  const float* bo       = (const float*)d_in[13];
  const float* g1       = (const float*)d_in[14];
  const float* b1       = (const float*)d_in[15];
  const float* w1       = (const float*)d_in[16];
  const float* bf1      = (const float*)d_in[17];
  const float* w2       = (const float*)d_in[18];
  const float* bf2      = (const float*)d_in[19];
  const float* g2       = (const float*)d_in[20];
  const float* b2       = (const float*)d_in[21];
  const float* fc_w     = (const float*)d_in[22];
  const float* fc_b     = (const float*)d_in[23];

  char* ws = (char*)d_ws;
  int*    fps_idx = (int*)(ws);                               // 16 KB
  int*    gidx    = (int*)(ws + (16u<<10));                   // 512 KB
  ushort* wfrag   = (ushort*)(ws + (1u<<20));                 // 1 MB  (bf16 weight frags)
  float*  xbuf    = (float*)(ws + (2u<<20));                  // 64 MB
  float*  fcout   = (float*)(ws + (66u<<20));                 // 4 MB
  float*  featT   = (float*)(ws + (70u<<20));                 // 32 MB (optional)
  const bool useT = ws_size >= ((size_t)102<<20);

  float* out0 = (float*)d_out;
  float* out1 = out0 + CB*3*CS;

  fps_kernel<<<CB, 1024, 0, stream>>>(xyz, fps_idx);
  knn_kernel<<<CB*CS, 256, 0, stream>>>(xyz, fps_idx, gidx);
  newxyz_kernel<<<(CB*3*CS + 255)/256, 256, 0, stream>>>(xyz, fps_idx, out0);
  wprep_kernel<<<256, 256, 0, stream>>>(wqkv, wo, w1, w2, wfrag);
  if (useT){
    dim3 tb(32, 8), tg(CN/32, CD/32, CB);
    transpose_kernel<<<tg, tb, 0, stream>>>(features, featT);
  }
  pe_kernel<<<CB*CS, 256, 0, stream>>>(xyz, features, useT ? featT : nullptr, gidx,
                                       pe_w1, pe_b1, bn_g, bn_b, bn_m, bn_v,
                                       pe_w2, pe_b2, xbuf);
  for (int L=0; L<4; L++){
    layer_mfma_kernel<<<CB*CS, 256, 0, stream>>>(xbuf,
        wfrag + (size_t)L*131072,
        bqkv + (size_t)L*3*CD, bo + (size_t)L*CD,
        g1 + (size_t)L*CD, b1 + (size_t)L*CD,
        bf1 + (size_t)L*CF, bf2 + (size_t)L*CD,
        g2 + (size_t)L*CD, b2 + (size_t)L*CD);
  }
  poolfc_kernel<<<CB*CS, 256, 0, stream>>>(xbuf, fc_w, fc_b, fcout);
  interp_kernel<<<(CB*CO*CN)/256, 256, 0, stream>>>(fcout, out1);
}

// Round 3
// 1543.001 us; speedup vs baseline: 3.6188x; 1.1777x over previous
//
#include <hip/hip_runtime.h>
#include <math.h>

constexpr int CB  = 8;     // batches
constexpr int CN  = 8192;  // points
constexpr int CS  = 512;   // npoint
constexpr int CK  = 32;    // nsample
constexpr int CD  = 128;   // dim
constexpr int CF  = 256;   // dff
constexpr int CO  = 256;   // dim_out
constexpr float CEPS = 1e-5f;

typedef __attribute__((ext_vector_type(8)))  short short8;
typedef __attribute__((ext_vector_type(4)))  float f32x4;
typedef __attribute__((ext_vector_type(16))) float f32x16;
#define MFMA16(a,b,c) __builtin_amdgcn_mfma_f32_16x16x32_bf16(a,b,c,0,0,0)
#define MFMA32(a,b,c) __builtin_amdgcn_mfma_f32_32x32x16_bf16(a,b,c,0,0,0)

__device__ __forceinline__ ushort f2b(float f){
  unsigned u = __builtin_bit_cast(unsigned, f);
  u = u + 0x7fffu + ((u >> 16) & 1u);
  return (ushort)(u >> 16);
}

// ---------------------------------------------------------------- FPS
// points in registers; packed u64 (dist|8191-idx) argmax => exact numpy
// first-occurrence tie-break with a single max-reduce chain.
__global__ __launch_bounds__(1024)
void fps_kernel(const float* __restrict__ xyz, int* __restrict__ fps_idx)
{
#pragma clang fp contract(off)
  __shared__ __align__(16) float4 p4[CN];          // 128 KB (centroid broadcast only)
  __shared__ unsigned long long wred[16];
  __shared__ int far_sh;
  const int b = blockIdx.x, t = threadIdx.x;
  const float* xb = xyz + (size_t)b*3*CN;
  float px[8], py[8], pz[8], dist[8];
  #pragma unroll
  for (int j=0;j<8;j++){
    const int i = t + 1024*j;
    px[j] = xb[i]; py[j] = xb[CN+i]; pz[j] = xb[2*CN+i];
    dist[j] = 1e10f;
    p4[i] = make_float4(px[j], py[j], pz[j], 0.f);
  }
  __syncthreads();
  int far = 0;
  for (int it = 0; it < CS; ++it){
    if (t == 0) fps_idx[b*CS + it] = far;
    const float4 c = p4[far];
    unsigned long long kk[8];
    #pragma unroll
    for (int j=0;j<8;j++){
      const float dx = px[j]-c.x, dy = py[j]-c.y, dz = pz[j]-c.z;
      const float d2 = (dx*dx + dy*dy) + dz*dz;
      const float nd = fminf(dist[j], d2);
      dist[j] = nd;
      kk[j] = ((unsigned long long)__builtin_bit_cast(unsigned, nd) << 32)
              | (unsigned)(8191 - (t + 1024*j));
    }
    #pragma unroll
    for (int st=1; st<8; st<<=1)
      #pragma unroll
      for (int j=0;j<8;j+=2*st)
        kk[j] = kk[j] >= kk[j+st] ? kk[j] : kk[j+st];
    unsigned long long key = kk[0];
    #pragma unroll
    for (int off=1; off<=32; off<<=1){
      const unsigned long long o = __shfl_xor(key, off);
      key = o > key ? o : key;
    }
    if ((t & 63) == 0) wred[t>>6] = key;
    __syncthreads();
    if (t < 64){
      unsigned long long k2 = (t < 16) ? wred[t] : 0ull;
      #pragma unroll
      for (int off=1; off<=8; off<<=1){
        const unsigned long long o = __shfl_xor(k2, off);
        k2 = o > k2 ? o : k2;
      }
      if (t == 0) far_sh = 8191 - (int)(k2 & 0xFFFFFFFFu);
    }
    __syncthreads();
    far = far_sh;
  }
}

// ---------------------------------------------------------------- kNN top-32
__global__ __launch_bounds__(256)
void knn_kernel(const float* __restrict__ xyz, const int* __restrict__ fps_idx,
                int* __restrict__ gidx)
{
#pragma clang fp contract(off)
  __shared__ float wv[4];
  __shared__ int   wi[4];
  __shared__ int   win_sh;
  const int blk = blockIdx.x, t = threadIdx.x;
  const int b = blk >> 9;
  const int s = blk & 511;
  const float* xb = xyz + (size_t)b*3*CN;
  const int cidx = fps_idx[b*CS + s];
  const float cx = xb[cidx], cy = xb[CN+cidx], cz = xb[2*CN+cidx];
  const float cn2 = (cx*cx + cy*cy) + cz*cz;
  float dv[32];
  float mv = 1e30f; int mi = 0;
  #pragma unroll
  for (int j=0;j<32;j++){
    const int i = t + 256*j;
    const float x = xb[i], y = xb[CN+i], z = xb[2*CN+i];
    const float pn2 = (x*x + y*y) + z*z;
    const float dot = (cx*x + cy*y) + cz*z;
    const float d2 = (cn2 + pn2) - 2.0f*dot;
    dv[j] = d2;
    if (d2 < mv || (d2 == mv && i < mi)){ mv = d2; mi = i; }
  }
  for (int k=0;k<CK;k++){
    float v = mv; int i = mi;
    #pragma unroll
    for (int off=32; off>=1; off>>=1){
      const float ov = __shfl_xor(v, off);
      const int   oi = __shfl_xor(i, off);
      if (ov < v || (ov == v && oi < i)){ v = ov; i = oi; }
    }
    if ((t & 63) == 0){ wv[t>>6] = v; wi[t>>6] = i; }
    __syncthreads();
    if (t == 0){
      #pragma unroll
      for (int w=1;w<4;w++)
        if (wv[w] < v || (wv[w] == v && wi[w] < i)){ v = wv[w]; i = wi[w]; }
      win_sh = i;
      gidx[(size_t)blk*CK + k] = i;
    }
    __syncthreads();
    const int win = win_sh;
    if ((win & 255) == t){
      const int jw = win >> 8;
      #pragma unroll
      for (int j=0;j<32;j++) if (j == jw) dv[j] = 1e30f;
      mv = 1e30f; mi = 0;
      #pragma unroll
      for (int j=0;j<32;j++){
        const int i2 = t + 256*j;
        if (dv[j] < mv || (dv[j] == mv && i2 < mi)){ mv = dv[j]; mi = i2; }
      }
    }
  }
}

// ---------------------------------------------------------------- new_xyz out
__global__ __launch_bounds__(256)
void newxyz_kernel(const float* __restrict__ xyz, const int* __restrict__ fps_idx,
                   float* __restrict__ out0)
{
  const int idx = blockIdx.x*256 + threadIdx.x;
  if (idx >= CB*3*CS) return;
  const int s = idx & 511;
  const int c = (idx >> 9) % 3;
  const int b = idx / (3*CS);
  const int n = fps_idx[b*CS + s];
  out0[idx] = xyz[(size_t)b*3*CN + (size_t)c*CN + n];
}

// ---------------------------------------------------------------- feature transpose [B,D,N] -> [B,N,D]
__global__ __launch_bounds__(256)
void transpose_kernel(const float* __restrict__ f, float* __restrict__ ft)
{
  __shared__ float tile[32][33];
  const int b = blockIdx.z, d0 = blockIdx.y*32, n0 = blockIdx.x*32;
  const int tx = threadIdx.x, ty = threadIdx.y;
  const float* fb = f + (size_t)b*CD*CN;
  #pragma unroll
  for (int r=0;r<32;r+=8) tile[ty+r][tx] = fb[(size_t)(d0+ty+r)*CN + n0+tx];
  __syncthreads();
  float* ftb = ft + (size_t)b*CN*CD;
  #pragma unroll
  for (int r=0;r<32;r+=8) ftb[(size_t)(n0+ty+r)*CD + d0+tx] = tile[tx][ty+r];
}

// ---------------------------------------------------------------- gather + positional encoding + add
__global__ __launch_bounds__(256)
void pe_kernel(const float* __restrict__ xyz, const float* __restrict__ features,
               const float* __restrict__ featT, const int* __restrict__ gidx,
               const float* __restrict__ pe_w1, const float* __restrict__ pe_b1,
               const float* __restrict__ bn_g, const float* __restrict__ bn_b,
               const float* __restrict__ bn_m, const float* __restrict__ bn_v,
               const float* __restrict__ pe_w2, const float* __restrict__ pe_b2,
               float* __restrict__ xout)
{
  __shared__ __align__(16) float w2s[CD*68];
  __shared__ __align__(16) float hr[CK*68];
  __shared__ int idxs[CK];
  __shared__ float gx[CK], gy[CK], gz[CK];
  const int g = blockIdx.x, t = threadIdx.x;
  const int b = g >> 9;
  for (int i=t; i<CD*64; i+=256) w2s[(i>>6)*68 + (i&63)] = pe_w2[i];
  if (t < CK){
    const int id = gidx[(size_t)g*CK + t];
    idxs[t] = id;
    const float* xb = xyz + (size_t)b*3*CN;
    gx[t] = xb[id]; gy[t] = xb[CN+id]; gz[t] = xb[2*CN+id];
  }
  __syncthreads();
  for (int v=t; v<CK*64; v+=256){
    const int k = v>>6, j = v&63;
    float h = ((gx[k]*pe_w1[j*3] + gy[k]*pe_w1[j*3+1]) + gz[k]*pe_w1[j*3+2]) + pe_b1[j];
    h = (h - bn_m[j]) / sqrtf(bn_v[j] + CEPS) * bn_g[j] + bn_b[j];
    hr[k*68+j] = fmaxf(h, 0.f);
  }
  __syncthreads();
  const float* fb  = features + (size_t)b*CD*CN;
  const float* ftb = featT ? (featT + (size_t)b*CN*CD) : nullptr;
  for (int p=t; p<CK*CD; p+=256){
    const int k = p>>7, d = p&127;
    const float4* hp = (const float4*)(hr  + k*68);
    const float4* wp = (const float4*)(w2s + d*68);
    float acc = 0.f;
    #pragma unroll
    for (int j=0;j<16;j++){
      const float4 a = hp[j], w = wp[j];
      acc += a.x*w.x; acc += a.y*w.y; acc += a.z*w.z; acc += a.w*w.w;
    }
    acc += pe_b2[d];
    const float gf = ftb ? ftb[(size_t)idxs[k]*CD + d] : fb[(size_t)d*CN + idxs[k]];
    xout[(size_t)g*CK*CD + p] = gf + acc;
  }
}

// ---------------------------------------------------------------- weight prep -> bf16 MFMA B-fragments
__global__ __launch_bounds__(256)
void wprep_kernel(const float* __restrict__ wqkv, const float* __restrict__ wo,
                  const float* __restrict__ w1,   const float* __restrict__ w2,
                  ushort* __restrict__ dst)
{
  const int tid = blockIdx.x*256 + threadIdx.x;   // 65536 threads
  const int l = tid & 63;
  const int f = tid >> 6;          // 0..1023
  const int L = f >> 8;
  const int r = f & 255;
  const float* src; int stride, nt, kt;
  if (r < 96)      { nt = r>>2;        kt = r&3;        src = wqkv + (size_t)L*384*128; stride = 128; }
  else if (r < 128){ nt = (r-96)>>2;   kt = (r-96)&3;   src = wo   + (size_t)L*128*128; stride = 128; }
  else if (r < 192){ nt = (r-128)>>2;  kt = (r-128)&3;  src = w1   + (size_t)L*256*128; stride = 128; }
  else             { nt = (r-192)>>3;  kt = (r-192)&7;  src = w2   + (size_t)L*128*256; stride = 256; }
  const int n = nt*16 + (l & 15);
  const int k = kt*32 + (l >> 4)*8;
  const float* p = src + (size_t)n*stride + k;
  uint4 o;
  o.x = (unsigned)f2b(p[0]) | ((unsigned)f2b(p[1])<<16);
  o.y = (unsigned)f2b(p[2]) | ((unsigned)f2b(p[3])<<16);
  o.z = (unsigned)f2b(p[4]) | ((unsigned)f2b(p[5])<<16);
  o.w = (unsigned)f2b(p[6]) | ((unsigned)f2b(p[7])<<16);
  *(uint4*)(dst + (size_t)tid*8) = o;
}

// ---------------------------------------------------------------- fused MFMA transformer layer
__device__ __forceinline__ void ln_inplace(float* x32s, ushort* xbv,
                                           const float* __restrict__ gamma,
                                           const float* __restrict__ beta, int t)
{
  const int r = t >> 3, j = t & 7;
  float v[16]; float s = 0.f;
  #pragma unroll
  for (int i=0;i<16;i++){ v[i] = x32s[r*132 + j + 8*i]; s += v[i]; }
  #pragma unroll
  for (int off=1; off<8; off<<=1) s += __shfl_xor(s, off);
  const float mean = s * (1.f/128.f);
  float var = 0.f;
  #pragma unroll
  for (int i=0;i<16;i++){ const float d = v[i]-mean; var += d*d; }
  #pragma unroll
  for (int off=1; off<8; off<<=1) var += __shfl_xor(var, off);
  const float inv = 1.f / sqrtf(var*(1.f/128.f) + CEPS);
  #pragma unroll
  for (int i=0;i<16;i++){
    const int d = j + 8*i;
    const float o = (v[i]-mean)*inv*gamma[d] + beta[d];
    x32s[r*132 + d] = o;
    xbv[r*136 + d] = f2b(o);
  }
}

__global__ __launch_bounds__(256, 2)
void layer_mfma_kernel(float* __restrict__ xbuf, const ushort* __restrict__ wf,
                       const float* __restrict__ bqkv, const float* __restrict__ bo,
                       const float* __restrict__ g1, const float* __restrict__ b1v,
                       const float* __restrict__ bf1, const float* __restrict__ bf2,
                       const float* __restrict__ g2, const float* __restrict__ b2v)
{
  __shared__ __align__(16) float  x32s[32*132];   // fp32 residual path
  __shared__ __align__(16) ushort xbv [32*136];   // bf16 A-operand buffer
  __shared__ __align__(16) ushort qk  [32*264];   // Q|K, later FFN1 out
  __shared__ __align__(16) ushort vT  [128*40];   // V transposed [dim][token]
  __shared__ __align__(16) ushort Pb  [4*32*40];  // per-wave P scratch
  const int g = blockIdx.x, t = threadIdx.x;
  const int w = t>>6, l = t&63;
  const int l15 = l&15, q4 = l>>4, l31 = l&31, hi = l>>5;
  float* xg = xbuf + (size_t)g*1024*4;
  const uint4* wfv = (const uint4*)wf;

  for (int i=t;i<1024;i+=256){
    const float4 v = ((const float4*)xg)[i];
    const int r = i>>5, c = (i&31)*4;
    *(float4*)&x32s[r*132 + c] = v;
    uint2 p;
    p.x = (unsigned)f2b(v.x) | ((unsigned)f2b(v.y)<<16);
    p.y = (unsigned)f2b(v.z) | ((unsigned)f2b(v.w)<<16);
    *(uint2*)&xbv[r*136 + c] = p;
  }
  __syncthreads();

  // ---- QKV
  {
    short8 a[2][4];
    #pragma unroll
    for (int mt=0;mt<2;mt++)
      #pragma unroll
      for (int kt=0;kt<4;kt++)
        a[mt][kt] = __builtin_bit_cast(short8, *(const uint4*)&xbv[(l15+16*mt)*136 + kt*32 + q4*8]);
    for (int i=0;i<6;i++){
      const int nt = w + 4*i;
      const int n  = nt*16 + l15;
      f32x4 a0 = {0.f,0.f,0.f,0.f}, a1 = {0.f,0.f,0.f,0.f};
      #pragma unroll
      for (int kt=0;kt<4;kt++){
        const short8 b = __builtin_bit_cast(short8, wfv[(nt*4+kt)*64 + l]);
        a0 = MFMA16(a[0][kt], b, a0);
        a1 = MFMA16(a[1][kt], b, a1);
      }
      const float bias = bqkv[n];
      if (nt < 16){
        #pragma unroll
        for (int i2=0;i2<4;i2++){
          qk[(q4*4+i2   )*264 + n] = f2b(a0[i2]+bias);
          qk[(q4*4+i2+16)*264 + n] = f2b(a1[i2]+bias);
        }
      } else {
        const int d = n - 256;
        uint2 p0, p1;
        p0.x = (unsigned)f2b(a0[0]+bias) | ((unsigned)f2b(a0[1]+bias)<<16);
        p0.y = (unsigned)f2b(a0[2]+bias) | ((unsigned)f2b(a0[3]+bias)<<16);
        p1.x = (unsigned)f2b(a1[0]+bias) | ((unsigned)f2b(a1[1]+bias)<<16);
        p1.y = (unsigned)f2b(a1[2]+bias) | ((unsigned)f2b(a1[3]+bias)<<16);
        *(uint2*)&vT[d*40 + q4*4]      = p0;
        *(uint2*)&vT[d*40 + 16 + q4*4] = p1;
      }
    }
  }
  __syncthreads();

  // ---- attention
  for (int hh=0; hh<2; hh++){
    const int h = 2*w + hh;
    const short8 ka = __builtin_bit_cast(short8, *(const uint4*)&qk[l31*264 + 128 + h*16 + hi*8]);
    const short8 qb = __builtin_bit_cast(short8, *(const uint4*)&qk[l31*264 +       h*16 + hi*8]);
    f32x16 s;
    #pragma unroll
    for (int i=0;i<16;i++) s[i] = 0.f;
    s = MFMA32(ka, qb, s);
    float e[16]; float mx = -1e30f;
    #pragma unroll
    for (int i=0;i<16;i++){ e[i] = s[i]*0.25f; mx = fmaxf(mx, e[i]); }
    mx = fmaxf(mx, __shfl_xor(mx, 32));
    float sum = 0.f;
    #pragma unroll
    for (int i=0;i<16;i++){ e[i] = __expf(e[i]-mx); sum += e[i]; }
    sum += __shfl_xor(sum, 32);
    const float inv = 1.f/sum;
    #pragma unroll
    for (int j=0;j<4;j++){
      uint2 p;
      p.x = (unsigned)f2b(e[4*j  ]*inv) | ((unsigned)f2b(e[4*j+1]*inv)<<16);
      p.y = (unsigned)f2b(e[4*j+2]*inv) | ((unsigned)f2b(e[4*j+3]*inv)<<16);
      *(uint2*)&Pb[w*1280 + l31*40 + j*8 + hi*4] = p;
    }
    const short8 bv = __builtin_bit_cast(short8, *(const uint4*)&vT[(h*16+l15)*40 + q4*8]);
    #pragma unroll
    for (int mt=0;mt<2;mt++){
      const short8 ap = __builtin_bit_cast(short8, *(const uint4*)&Pb[w*1280 + (l15+16*mt)*40 + q4*8]);
      f32x4 o = {0.f,0.f,0.f,0.f};
      o = MFMA16(ap, bv, o);
      #pragma unroll
      for (int i2=0;i2<4;i2++)
        xbv[(16*mt + q4*4 + i2)*136 + h*16 + l15] = f2b(o[i2]);
    }
  }
  __syncthreads();

  // ---- O-proj + residual
  {
    short8 a[2][4];
    #pragma unroll
    for (int mt=0;mt<2;mt++)
      #pragma unroll
      for (int kt=0;kt<4;kt++)
        a[mt][kt] = __builtin_bit_cast(short8, *(const uint4*)&xbv[(l15+16*mt)*136 + kt*32 + q4*8]);
    for (int i=0;i<2;i++){
      const int nt = w + 4*i;
      const int n  = nt*16 + l15;
      f32x4 a0 = {0.f,0.f,0.f,0.f}, a1 = {0.f,0.f,0.f,0.f};
      #pragma unroll
      for (int kt=0;kt<4;kt++){
        const short8 b = __builtin_bit_cast(short8, wfv[(96 + nt*4+kt)*64 + l]);
        a0 = MFMA16(a[0][kt], b, a0);
        a1 = MFMA16(a[1][kt], b, a1);
      }
      const float bias = bo[n];
      #pragma unroll
      for (int i2=0;i2<4;i2++){
        x32s[(q4*4+i2   )*132 + n] += a0[i2] + bias;
        x32s[(q4*4+i2+16)*132 + n] += a1[i2] + bias;
      }
    }
  }
  __syncthreads();
  ln_inplace(x32s, xbv, g1, b1v, t);
  __syncthreads();

  // ---- FFN1 + relu
  {
    short8 a[2][4];
    #pragma unroll
    for (int mt=0;mt<2;mt++)
      #pragma unroll
      for (int kt=0;kt<4;kt++)
        a[mt][kt] = __builtin_bit_cast(short8, *(const uint4*)&xbv[(l15+16*mt)*136 + kt*32 + q4*8]);
    for (int i=0;i<4;i++){
      const int nt = w + 4*i;
      const int n  = nt*16 + l15;
      f32x4 a0 = {0.f,0.f,0.f,0.f}, a1 = {0.f,0.f,0.f,0.f};
      #pragma unroll
      for (int kt=0;kt<4;kt++){
        const short8 b = __builtin_bit_cast(short8, wfv[(128 + nt*4+kt)*64 + l]);
        a0 = MFMA16(a[0][kt], b, a0);
        a1 = MFMA16(a[1][kt], b, a1);
      }
      const float bias = bf1[n];
      #pragma unroll
      for (int i2=0;i2<4;i2++){
        qk[(q4*4+i2   )*264 + n] = f2b(fmaxf(a0[i2]+bias, 0.f));
        qk[(q4*4+i2+16)*264 + n] = f2b(fmaxf(a1[i2]+bias, 0.f));
      }
    }
  }
  __syncthreads();

  // ---- FFN2 + residual, K=256
  {
    short8 a[2][8];
    #pragma unroll
    for (int mt=0;mt<2;mt++)
      #pragma unroll
      for (int kt=0;kt<8;kt++)
        a[mt][kt] = __builtin_bit_cast(short8, *(const uint4*)&qk[(l15+16*mt)*264 + kt*32 + q4*8]);
    for (int i=0;i<2;i++){
      const int nt = w + 4*i;
      const int n  = nt*16 + l15;
      f32x4 a0 = {0.f,0.f,0.f,0.f}, a1 = {0.f,0.f,0.f,0.f};
      #pragma unroll
      for (int kt=0;kt<8;kt++){
        const short8 b = __builtin_bit_cast(short8, wfv[(192 + nt*8+kt)*64 + l]);
        a0 = MFMA16(a[0][kt], b, a0);
        a1 = MFMA16(a[1][kt], b, a1);
      }
      const float bias = bf2[n];
      #pragma unroll
      for (int i2=0;i2<4;i2++){
        x32s[(q4*4+i2   )*132 + n] += a0[i2] + bias;
        x32s[(q4*4+i2+16)*132 + n] += a1[i2] + bias;
      }
    }
  }
  __syncthreads();
  ln_inplace(x32s, xbv, g2, b2v, t);
  __syncthreads();

  for (int i=t;i<1024;i+=256){
    const int r = i>>5, c = (i&31)*4;
    ((float4*)xg)[i] = *(const float4*)&x32s[r*132 + c];
  }
}

// ---------------------------------------------------------------- max-pool + fc
__global__ __launch_bounds__(256)
void poolfc_kernel(const float* __restrict__ xbuf, const float* __restrict__ fc_w,
                   const float* __restrict__ fc_b, float* __restrict__ fcout)
{
  __shared__ __align__(16) float pooled[CD];
  const int gg = blockIdx.x, t = threadIdx.x;
  const float* xg = xbuf + (size_t)gg*CK*CD;
  if (t < CD){
    float m = -1e30f;
    for (int k=0;k<CK;k++) m = fmaxf(m, xg[(size_t)k*CD + t]);
    pooled[t] = m;
  }
  __syncthreads();
  const float* wr = fc_w + (size_t)t*CD;
  float acc = 0.f;
  const float4* pp = (const float4*)pooled;
  for (int i=0;i<CD/4;i++){
    const float4 w4 = *(const float4*)(wr + 4*i);
    const float4 p4 = pp[i];
    acc += p4.x*w4.x; acc += p4.y*w4.y; acc += p4.z*w4.z; acc += p4.w*w4.w;
  }
  acc += fc_b[t];
  const int b = gg >> 9, s = gg & 511;
  fcout[((size_t)b*CS + s)*CO + t] = acc;
}

// ---------------------------------------------------------------- linear interp S -> N
__global__ __launch_bounds__(256)
void interp_kernel(const float* __restrict__ fcout, float* __restrict__ out1)
{
  const int idx = blockIdx.x*256 + threadIdx.x;
  const int n  = idx & (CN-1);
  const int bo = idx >> 13;
  const int b  = bo >> 8, o = bo & 255;
  const double pos = (double)n * ((double)(CS-1)/(double)(CN-1));
  const int i0 = (int)pos;
  const int i1 = min(i0+1, CS-1);
  const float w = (float)(pos - (double)i0);
  const float v0 = fcout[((size_t)b*CS + i0)*CO + o];
  const float v1 = fcout[((size_t)b*CS + i1)*CO + o];
  out1[idx] = v0*(1.f - w) + v1*w;
}

// ---------------------------------------------------------------- launcher
extern "C" void kernel_launch(void* const* d_in, const int* in_sizes, int n_in,
                              void* d_out, int out_size, void* d_ws, size_t ws_size,
                              hipStream_t stream)
{
  (void)in_sizes; (void)n_in; (void)out_size;
  const float* xyz      = (const float*)d_in[0];
  const float* features = (const float*)d_in[1];
  const float* pe_w1    = (const float*)d_in[2];
  const float* pe_b1    = (const float*)d_in[3];
  const float* bn_g     = (const float*)d_in[4];
  const float* bn_b     = (const float*)d_in[5];
  const float* bn_m     = (const float*)d_in[6];
  const float* bn_v     = (const float*)d_in[7];
  const float* pe_w2    = (const float*)d_in[8];
  const float* pe_b2    = (const float*)d_in[9];
  const float* wqkv     = (const float*)d_in[10];
  const float* bqkv     = (const float*)d_in[11];
  const float* wo       = (const float*)d_in[12];
  const float* bo       = (const float*)d_in[13];
  const float* g1       = (const float*)d_in[14];
  const float* b1       = (const float*)d_in[15];
  const float* w1       = (const float*)d_in[16];
  const float* bf1      = (const float*)d_in[17];
  const float* w2       = (const float*)d_in[18];
  const float* bf2      = (const float*)d_in[19];
  const float* g2       = (const float*)d_in[20];
  const float* b2       = (const float*)d_in[21];
  const float* fc_w     = (const float*)d_in[22];
  const float* fc_b     = (const float*)d_in[23];

  char* ws = (char*)d_ws;
  int*    fps_idx = (int*)(ws);                               // 16 KB
  int*    gidx    = (int*)(ws + (16u<<10));                   // 512 KB
  ushort* wfrag   = (ushort*)(ws + (1u<<20));                 // 1 MB
  float*  xbuf    = (float*)(ws + (2u<<20));                  // 64 MB
  float*  fcout   = (float*)(ws + (66u<<20));                 // 4 MB
  float*  featT   = (float*)(ws + (70u<<20));                 // 32 MB (optional)
  const bool useT = ws_size >= ((size_t)102<<20);

  float* out0 = (float*)d_out;
  float* out1 = out0 + CB*3*CS;

  fps_kernel<<<CB, 1024, 0, stream>>>(xyz, fps_idx);
  knn_kernel<<<CB*CS, 256, 0, stream>>>(xyz, fps_idx, gidx);
  newxyz_kernel<<<(CB*3*CS + 255)/256, 256, 0, stream>>>(xyz, fps_idx, out0);
  wprep_kernel<<<256, 256, 0, stream>>>(wqkv, wo, w1, w2, wfrag);
  if (useT){
    dim3 tb(32, 8), tg(CN/32, CD/32, CB);
    transpose_kernel<<<tg, tb, 0, stream>>>(features, featT);
  }
  pe_kernel<<<CB*CS, 256, 0, stream>>>(xyz, features, useT ? featT : nullptr, gidx,
                                       pe_w1, pe_b1, bn_g, bn_b, bn_m, bn_v,
                                       pe_w2, pe_b2, xbuf);
  for (int L=0; L<4; L++){
    layer_mfma_kernel<<<CB*CS, 256, 0, stream>>>(xbuf,
        wfrag + (size_t)L*131072,
        bqkv + (size_t)L*3*CD, bo + (size_t)L*CD,
        g1 + (size_t)L*CD, b1 + (size_t)L*CD,
        bf1 + (size_t)L*CF, bf2 + (size_t)L*CD,
        g2 + (size_t)L*CD, b2 + (size_t)L*CD);
  }
  poolfc_kernel<<<CB*CS, 256, 0, stream>>>(xbuf, fc_w, fc_b, fcout);
  interp_kernel<<<(CB*CO*CN)/256, 256, 0, stream>>>(fcout, out1);
}

// Round 4
// 1481.662 us; speedup vs baseline: 3.7686x; 1.0414x over previous
//
#include <hip/hip_runtime.h>
#include <math.h>

constexpr int CB  = 8;     // batches
constexpr int CN  = 8192;  // points
constexpr int CS  = 512;   // npoint
constexpr int CK  = 32;    // nsample
constexpr int CD  = 128;   // dim
constexpr int CF  = 256;   // dff
constexpr int CO  = 256;   // dim_out
constexpr float CEPS = 1e-5f;

typedef __attribute__((ext_vector_type(8)))  short short8;
typedef __attribute__((ext_vector_type(4)))  float f32x4;
typedef __attribute__((ext_vector_type(16))) float f32x16;
#define MFMA16(a,b,c) __builtin_amdgcn_mfma_f32_16x16x32_bf16(a,b,c,0,0,0)
#define MFMA32(a,b,c) __builtin_amdgcn_mfma_f32_32x32x16_bf16(a,b,c,0,0,0)

__device__ __forceinline__ ushort f2b(float f){
  unsigned u = __builtin_bit_cast(unsigned, f);
  u = u + 0x7fffu + ((u >> 16) & 1u);
  return (ushort)(u >> 16);
}

// ---------------------------------------------------------------- FPS v3
// 512 threads x 16 pts in registers. One barrier/iter: parity-double-buffered
// per-wave maxima; every wave redundantly reduces the 8 keys (no broadcast).
// Packed u64 key (dist_bits<<32 | 8191-idx) == numpy argmax + first-occurrence.
__global__ __launch_bounds__(512)
void fps_kernel(const float* __restrict__ xyz, int* __restrict__ fps_idx)
{
#pragma clang fp contract(off)
  __shared__ __align__(16) float4 p4[CN];          // centroid broadcast table
  __shared__ unsigned long long wred[2][8];
  const int b = blockIdx.x, t = threadIdx.x;
  const int w = t >> 6, lane = t & 63;
  const float* xb = xyz + (size_t)b*3*CN;
  float px[16], py[16], pz[16], dist[16];
  #pragma unroll
  for (int j=0;j<16;j++){
    const int i = t + 512*j;
    px[j] = xb[i]; py[j] = xb[CN+i]; pz[j] = xb[2*CN+i];
    dist[j] = 1e10f;
    p4[i] = make_float4(px[j], py[j], pz[j], 0.f);
  }
  __syncthreads();
  int far = 0, par = 0;
  float4 c = p4[0];
  for (int it = 0; it < CS; ++it){
    if (t == 0) fps_idx[b*CS + it] = far;
    unsigned long long kk[16];
    #pragma unroll
    for (int j=0;j<16;j++){
      const float dx = px[j]-c.x, dy = py[j]-c.y, dz = pz[j]-c.z;
      const float d2 = (dx*dx + dy*dy) + dz*dz;
      const float nd = fminf(dist[j], d2);
      dist[j] = nd;
      kk[j] = ((unsigned long long)__builtin_bit_cast(unsigned, nd) << 32)
              | (unsigned)(8191 - (t + 512*j));
    }
    #pragma unroll
    for (int st=1; st<16; st<<=1)
      #pragma unroll
      for (int j=0;j<16;j+=2*st)
        kk[j] = kk[j] >= kk[j+st] ? kk[j] : kk[j+st];
    unsigned long long key = kk[0];
    #pragma unroll
    for (int off=1; off<=32; off<<=1){
      const unsigned long long o = __shfl_xor(key, off);
      key = o > key ? o : key;
    }
    if (lane == 0) wred[par][w] = key;
    __syncthreads();
    unsigned long long k2 = wred[par][lane & 7];
    #pragma unroll
    for (int off=1; off<=4; off<<=1){
      const unsigned long long o = __shfl_xor(k2, off);
      k2 = o > k2 ? o : k2;
    }
    far = 8191 - (int)(k2 & 0xFFFFFFFFu);
    c = p4[far];
    par ^= 1;
  }
}

// ---------------------------------------------------------------- kNN top-32
__global__ __launch_bounds__(256)
void knn_kernel(const float* __restrict__ xyz, const int* __restrict__ fps_idx,
                int* __restrict__ gidx)
{
#pragma clang fp contract(off)
  __shared__ float wv[4];
  __shared__ int   wi[4];
  __shared__ int   win_sh;
  const int blk = blockIdx.x, t = threadIdx.x;
  const int b = blk >> 9;
  const int s = blk & 511;
  const float* xb = xyz + (size_t)b*3*CN;
  const int cidx = fps_idx[b*CS + s];
  const float cx = xb[cidx], cy = xb[CN+cidx], cz = xb[2*CN+cidx];
  const float cn2 = (cx*cx + cy*cy) + cz*cz;
  float dv[32];
  float mv = 1e30f; int mi = 0;
  #pragma unroll
  for (int j=0;j<32;j++){
    const int i = t + 256*j;
    const float x = xb[i], y = xb[CN+i], z = xb[2*CN+i];
    const float pn2 = (x*x + y*y) + z*z;
    const float dot = (cx*x + cy*y) + cz*z;
    const float d2 = (cn2 + pn2) - 2.0f*dot;
    dv[j] = d2;
    if (d2 < mv || (d2 == mv && i < mi)){ mv = d2; mi = i; }
  }
  for (int k=0;k<CK;k++){
    float v = mv; int i = mi;
    #pragma unroll
    for (int off=32; off>=1; off>>=1){
      const float ov = __shfl_xor(v, off);
      const int   oi = __shfl_xor(i, off);
      if (ov < v || (ov == v && oi < i)){ v = ov; i = oi; }
    }
    if ((t & 63) == 0){ wv[t>>6] = v; wi[t>>6] = i; }
    __syncthreads();
    if (t == 0){
      #pragma unroll
      for (int w=1;w<4;w++)
        if (wv[w] < v || (wv[w] == v && wi[w] < i)){ v = wv[w]; i = wi[w]; }
      win_sh = i;
      gidx[(size_t)blk*CK + k] = i;
    }
    __syncthreads();
    const int win = win_sh;
    if ((win & 255) == t){
      const int jw = win >> 8;
      #pragma unroll
      for (int j=0;j<32;j++) if (j == jw) dv[j] = 1e30f;
      mv = 1e30f; mi = 0;
      #pragma unroll
      for (int j=0;j<32;j++){
        const int i2 = t + 256*j;
        if (dv[j] < mv || (dv[j] == mv && i2 < mi)){ mv = dv[j]; mi = i2; }
      }
    }
  }
}

// ---------------------------------------------------------------- new_xyz out
__global__ __launch_bounds__(256)
void newxyz_kernel(const float* __restrict__ xyz, const int* __restrict__ fps_idx,
                   float* __restrict__ out0)
{
  const int idx = blockIdx.x*256 + threadIdx.x;
  if (idx >= CB*3*CS) return;
  const int s = idx & 511;
  const int c = (idx >> 9) % 3;
  const int b = idx / (3*CS);
  const int n = fps_idx[b*CS + s];
  out0[idx] = xyz[(size_t)b*3*CN + (size_t)c*CN + n];
}

// ---------------------------------------------------------------- feature transpose [B,D,N] -> [B,N,D]
__global__ __launch_bounds__(256)
void transpose_kernel(const float* __restrict__ f, float* __restrict__ ft)
{
  __shared__ float tile[32][33];
  const int b = blockIdx.z, d0 = blockIdx.y*32, n0 = blockIdx.x*32;
  const int tx = threadIdx.x, ty = threadIdx.y;
  const float* fb = f + (size_t)b*CD*CN;
  #pragma unroll
  for (int r=0;r<32;r+=8) tile[ty+r][tx] = fb[(size_t)(d0+ty+r)*CN + n0+tx];
  __syncthreads();
  float* ftb = ft + (size_t)b*CN*CD;
  #pragma unroll
  for (int r=0;r<32;r+=8) ftb[(size_t)(n0+ty+r)*CD + d0+tx] = tile[tx][ty+r];
}

// ---------------------------------------------------------------- gather + positional encoding + add
__global__ __launch_bounds__(256)
void pe_kernel(const float* __restrict__ xyz, const float* __restrict__ features,
               const float* __restrict__ featT, const int* __restrict__ gidx,
               const float* __restrict__ pe_w1, const float* __restrict__ pe_b1,
               const float* __restrict__ bn_g, const float* __restrict__ bn_b,
               const float* __restrict__ bn_m, const float* __restrict__ bn_v,
               const float* __restrict__ pe_w2, const float* __restrict__ pe_b2,
               float* __restrict__ xout)
{
  __shared__ __align__(16) float w2s[CD*68];
  __shared__ __align__(16) float hr[CK*68];
  __shared__ int idxs[CK];
  __shared__ float gx[CK], gy[CK], gz[CK];
  const int g = blockIdx.x, t = threadIdx.x;
  const int b = g >> 9;
  for (int i=t; i<CD*64; i+=256) w2s[(i>>6)*68 + (i&63)] = pe_w2[i];
  if (t < CK){
    const int id = gidx[(size_t)g*CK + t];
    idxs[t] = id;
    const float* xb = xyz + (size_t)b*3*CN;
    gx[t] = xb[id]; gy[t] = xb[CN+id]; gz[t] = xb[2*CN+id];
  }
  __syncthreads();
  for (int v=t; v<CK*64; v+=256){
    const int k = v>>6, j = v&63;
    float h = ((gx[k]*pe_w1[j*3] + gy[k]*pe_w1[j*3+1]) + gz[k]*pe_w1[j*3+2]) + pe_b1[j];
    h = (h - bn_m[j]) / sqrtf(bn_v[j] + CEPS) * bn_g[j] + bn_b[j];
    hr[k*68+j] = fmaxf(h, 0.f);
  }
  __syncthreads();
  const float* fb  = features + (size_t)b*CD*CN;
  const float* ftb = featT ? (featT + (size_t)b*CN*CD) : nullptr;
  for (int p=t; p<CK*CD; p+=256){
    const int k = p>>7, d = p&127;
    const float4* hp = (const float4*)(hr  + k*68);
    const float4* wp = (const float4*)(w2s + d*68);
    float acc = 0.f;
    #pragma unroll
    for (int j=0;j<16;j++){
      const float4 a = hp[j], w = wp[j];
      acc += a.x*w.x; acc += a.y*w.y; acc += a.z*w.z; acc += a.w*w.w;
    }
    acc += pe_b2[d];
    const float gf = ftb ? ftb[(size_t)idxs[k]*CD + d] : fb[(size_t)d*CN + idxs[k]];
    xout[(size_t)g*CK*CD + p] = gf + acc;
  }
}

// ---------------------------------------------------------------- weight prep -> bf16 MFMA B-fragments
__global__ __launch_bounds__(256)
void wprep_kernel(const float* __restrict__ wqkv, const float* __restrict__ wo,
                  const float* __restrict__ w1,   const float* __restrict__ w2,
                  ushort* __restrict__ dst)
{
  const int tid = blockIdx.x*256 + threadIdx.x;   // 65536 threads
  const int l = tid & 63;
  const int f = tid >> 6;          // 0..1023
  const int L = f >> 8;
  const int r = f & 255;
  const float* src; int stride, nt, kt;
  if (r < 96)      { nt = r>>2;        kt = r&3;        src = wqkv + (size_t)L*384*128; stride = 128; }
  else if (r < 128){ nt = (r-96)>>2;   kt = (r-96)&3;   src = wo   + (size_t)L*128*128; stride = 128; }
  else if (r < 192){ nt = (r-128)>>2;  kt = (r-128)&3;  src = w1   + (size_t)L*256*128; stride = 128; }
  else             { nt = (r-192)>>3;  kt = (r-192)&7;  src = w2   + (size_t)L*128*256; stride = 256; }
  const int n = nt*16 + (l & 15);
  const int k = kt*32 + (l >> 4)*8;
  const float* p = src + (size_t)n*stride + k;
  uint4 o;
  o.x = (unsigned)f2b(p[0]) | ((unsigned)f2b(p[1])<<16);
  o.y = (unsigned)f2b(p[2]) | ((unsigned)f2b(p[3])<<16);
  o.z = (unsigned)f2b(p[4]) | ((unsigned)f2b(p[5])<<16);
  o.w = (unsigned)f2b(p[6]) | ((unsigned)f2b(p[7])<<16);
  *(uint4*)(dst + (size_t)tid*8) = o;
}

// ---------------------------------------------------------------- fused MFMA transformer layer
__device__ __forceinline__ void ln_inplace(float* x32s, ushort* xbv,
                                           const float* __restrict__ gamma,
                                           const float* __restrict__ beta, int t)
{
  const int r = t >> 3, j = t & 7;
  float v[16]; float s = 0.f;
  #pragma unroll
  for (int i=0;i<16;i++){ v[i] = x32s[r*132 + j + 8*i]; s += v[i]; }
  #pragma unroll
  for (int off=1; off<8; off<<=1) s += __shfl_xor(s, off);
  const float mean = s * (1.f/128.f);
  float var = 0.f;
  #pragma unroll
  for (int i=0;i<16;i++){ const float d = v[i]-mean; var += d*d; }
  #pragma unroll
  for (int off=1; off<8; off<<=1) var += __shfl_xor(var, off);
  const float inv = 1.f / sqrtf(var*(1.f/128.f) + CEPS);
  #pragma unroll
  for (int i=0;i<16;i++){
    const int d = j + 8*i;
    const float o = (v[i]-mean)*inv*gamma[d] + beta[d];
    x32s[r*132 + d] = o;
    xbv[r*136 + d] = f2b(o);
  }
}

__global__ __launch_bounds__(256, 2)
void layer_mfma_kernel(float* __restrict__ xbuf, const ushort* __restrict__ wf,
                       const float* __restrict__ bqkv, const float* __restrict__ bo,
                       const float* __restrict__ g1, const float* __restrict__ b1v,
                       const float* __restrict__ bf1, const float* __restrict__ bf2,
                       const float* __restrict__ g2, const float* __restrict__ b2v)
{
  __shared__ __align__(16) float  x32s[32*132];   // fp32 residual path
  __shared__ __align__(16) ushort xbv [32*136];   // bf16 A-operand buffer
  __shared__ __align__(16) ushort qk  [32*264];   // Q|K, later FFN1 out
  __shared__ __align__(16) ushort vT  [128*40];   // V transposed [dim][token]
  __shared__ __align__(16) ushort Pb  [4*32*40];  // per-wave P scratch
  const int g = blockIdx.x, t = threadIdx.x;
  const int w = t>>6, l = t&63;
  const int l15 = l&15, q4 = l>>4, l31 = l&31, hi = l>>5;
  float* xg = xbuf + (size_t)g*1024*4;
  const uint4* wfv = (const uint4*)wf;

  for (int i=t;i<1024;i+=256){
    const float4 v = ((const float4*)xg)[i];
    const int r = i>>5, c = (i&31)*4;
    *(float4*)&x32s[r*132 + c] = v;
    uint2 p;
    p.x = (unsigned)f2b(v.x) | ((unsigned)f2b(v.y)<<16);
    p.y = (unsigned)f2b(v.z) | ((unsigned)f2b(v.w)<<16);
    *(uint2*)&xbv[r*136 + c] = p;
  }
  __syncthreads();

  // ---- QKV
  {
    short8 a[2][4];
    #pragma unroll
    for (int mt=0;mt<2;mt++)
      #pragma unroll
      for (int kt=0;kt<4;kt++)
        a[mt][kt] = __builtin_bit_cast(short8, *(const uint4*)&xbv[(l15+16*mt)*136 + kt*32 + q4*8]);
    for (int i=0;i<6;i++){
      const int nt = w + 4*i;
      const int n  = nt*16 + l15;
      f32x4 a0 = {0.f,0.f,0.f,0.f}, a1 = {0.f,0.f,0.f,0.f};
      #pragma unroll
      for (int kt=0;kt<4;kt++){
        const short8 b = __builtin_bit_cast(short8, wfv[(nt*4+kt)*64 + l]);
        a0 = MFMA16(a[0][kt], b, a0);
        a1 = MFMA16(a[1][kt], b, a1);
      }
      const float bias = bqkv[n];
      if (nt < 16){
        #pragma unroll
        for (int i2=0;i2<4;i2++){
          qk[(q4*4+i2   )*264 + n] = f2b(a0[i2]+bias);
          qk[(q4*4+i2+16)*264 + n] = f2b(a1[i2]+bias);
        }
      } else {
        const int d = n - 256;
        uint2 p0, p1;
        p0.x = (unsigned)f2b(a0[0]+bias) | ((unsigned)f2b(a0[1]+bias)<<16);
        p0.y = (unsigned)f2b(a0[2]+bias) | ((unsigned)f2b(a0[3]+bias)<<16);
        p1.x = (unsigned)f2b(a1[0]+bias) | ((unsigned)f2b(a1[1]+bias)<<16);
        p1.y = (unsigned)f2b(a1[2]+bias) | ((unsigned)f2b(a1[3]+bias)<<16);
        *(uint2*)&vT[d*40 + q4*4]      = p0;
        *(uint2*)&vT[d*40 + 16 + q4*4] = p1;
      }
    }
  }
  __syncthreads();

  // ---- attention
  for (int hh=0; hh<2; hh++){
    const int h = 2*w + hh;
    const short8 ka = __builtin_bit_cast(short8, *(const uint4*)&qk[l31*264 + 128 + h*16 + hi*8]);
    const short8 qb = __builtin_bit_cast(short8, *(const uint4*)&qk[l31*264 +       h*16 + hi*8]);
    f32x16 s;
    #pragma unroll
    for (int i=0;i<16;i++) s[i] = 0.f;
    s = MFMA32(ka, qb, s);
    float e[16]; float mx = -1e30f;
    #pragma unroll
    for (int i=0;i<16;i++){ e[i] = s[i]*0.25f; mx = fmaxf(mx, e[i]); }
    mx = fmaxf(mx, __shfl_xor(mx, 32));
    float sum = 0.f;
    #pragma unroll
    for (int i=0;i<16;i++){ e[i] = __expf(e[i]-mx); sum += e[i]; }
    sum += __shfl_xor(sum, 32);
    const float inv = 1.f/sum;
    #pragma unroll
    for (int j=0;j<4;j++){
      uint2 p;
      p.x = (unsigned)f2b(e[4*j  ]*inv) | ((unsigned)f2b(e[4*j+1]*inv)<<16);
      p.y = (unsigned)f2b(e[4*j+2]*inv) | ((unsigned)f2b(e[4*j+3]*inv)<<16);
      *(uint2*)&Pb[w*1280 + l31*40 + j*8 + hi*4] = p;
    }
    const short8 bv = __builtin_bit_cast(short8, *(const uint4*)&vT[(h*16+l15)*40 + q4*8]);
    #pragma unroll
    for (int mt=0;mt<2;mt++){
      const short8 ap = __builtin_bit_cast(short8, *(const uint4*)&Pb[w*1280 + (l15+16*mt)*40 + q4*8]);
      f32x4 o = {0.f,0.f,0.f,0.f};
      o = MFMA16(ap, bv, o);
      #pragma unroll
      for (int i2=0;i2<4;i2++)
        xbv[(16*mt + q4*4 + i2)*136 + h*16 + l15] = f2b(o[i2]);
    }
  }
  __syncthreads();

  // ---- O-proj + residual
  {
    short8 a[2][4];
    #pragma unroll
    for (int mt=0;mt<2;mt++)
      #pragma unroll
      for (int kt=0;kt<4;kt++)
        a[mt][kt] = __builtin_bit_cast(short8, *(const uint4*)&xbv[(l15+16*mt)*136 + kt*32 + q4*8]);
    for (int i=0;i<2;i++){
      const int nt = w + 4*i;
      const int n  = nt*16 + l15;
      f32x4 a0 = {0.f,0.f,0.f,0.f}, a1 = {0.f,0.f,0.f,0.f};
      #pragma unroll
      for (int kt=0;kt<4;kt++){
        const short8 b = __builtin_bit_cast(short8, wfv[(96 + nt*4+kt)*64 + l]);
        a0 = MFMA16(a[0][kt], b, a0);
        a1 = MFMA16(a[1][kt], b, a1);
      }
      const float bias = bo[n];
      #pragma unroll
      for (int i2=0;i2<4;i2++){
        x32s[(q4*4+i2   )*132 + n] += a0[i2] + bias;
        x32s[(q4*4+i2+16)*132 + n] += a1[i2] + bias;
      }
    }
  }
  __syncthreads();
  ln_inplace(x32s, xbv, g1, b1v, t);
  __syncthreads();

  // ---- FFN1 + relu
  {
    short8 a[2][4];
    #pragma unroll
    for (int mt=0;mt<2;mt++)
      #pragma unroll
      for (int kt=0;kt<4;kt++)
        a[mt][kt] = __builtin_bit_cast(short8, *(const uint4*)&xbv[(l15+16*mt)*136 + kt*32 + q4*8]);
    for (int i=0;i<4;i++){
      const int nt = w + 4*i;
      const int n  = nt*16 + l15;
      f32x4 a0 = {0.f,0.f,0.f,0.f}, a1 = {0.f,0.f,0.f,0.f};
      #pragma unroll
      for (int kt=0;kt<4;kt++){
        const short8 b = __builtin_bit_cast(short8, wfv[(128 + nt*4+kt)*64 + l]);
        a0 = MFMA16(a[0][kt], b, a0);
        a1 = MFMA16(a[1][kt], b, a1);
      }
      const float bias = bf1[n];
      #pragma unroll
      for (int i2=0;i2<4;i2++){
        qk[(q4*4+i2   )*264 + n] = f2b(fmaxf(a0[i2]+bias, 0.f));
        qk[(q4*4+i2+16)*264 + n] = f2b(fmaxf(a1[i2]+bias, 0.f));
      }
    }
  }
  __syncthreads();

  // ---- FFN2 + residual, K=256
  {
    short8 a[2][8];
    #pragma unroll
    for (int mt=0;mt<2;mt++)
      #pragma unroll
      for (int kt=0;kt<8;kt++)
        a[mt][kt] = __builtin_bit_cast(short8, *(const uint4*)&qk[(l15+16*mt)*264 + kt*32 + q4*8]);
    for (int i=0;i<2;i++){
      const int nt = w + 4*i;
      const int n  = nt*16 + l15;
      f32x4 a0 = {0.f,0.f,0.f,0.f}, a1 = {0.f,0.f,0.f,0.f};
      #pragma unroll
      for (int kt=0;kt<8;kt++){
        const short8 b = __builtin_bit_cast(short8, wfv[(192 + nt*8+kt)*64 + l]);
        a0 = MFMA16(a[0][kt], b, a0);
        a1 = MFMA16(a[1][kt], b, a1);
      }
      const float bias = bf2[n];
      #pragma unroll
      for (int i2=0;i2<4;i2++){
        x32s[(q4*4+i2   )*132 + n] += a0[i2] + bias;
        x32s[(q4*4+i2+16)*132 + n] += a1[i2] + bias;
      }
    }
  }
  __syncthreads();
  ln_inplace(x32s, xbv, g2, b2v, t);
  __syncthreads();

  for (int i=t;i<1024;i+=256){
    const int r = i>>5, c = (i&31)*4;
    ((float4*)xg)[i] = *(const float4*)&x32s[r*132 + c];
  }
}

// ---------------------------------------------------------------- max-pool + fc
__global__ __launch_bounds__(256)
void poolfc_kernel(const float* __restrict__ xbuf, const float* __restrict__ fc_w,
                   const float* __restrict__ fc_b, float* __restrict__ fcout)
{
  __shared__ __align__(16) float pooled[CD];
  const int gg = blockIdx.x, t = threadIdx.x;
  const float* xg = xbuf + (size_t)gg*CK*CD;
  if (t < CD){
    float m = -1e30f;
    for (int k=0;k<CK;k++) m = fmaxf(m, xg[(size_t)k*CD + t]);
    pooled[t] = m;
  }
  __syncthreads();
  const float* wr = fc_w + (size_t)t*CD;
  float acc = 0.f;
  const float4* pp = (const float4*)pooled;
  for (int i=0;i<CD/4;i++){
    const float4 w4 = *(const float4*)(wr + 4*i);
    const float4 p4 = pp[i];
    acc += p4.x*w4.x; acc += p4.y*w4.y; acc += p4.z*w4.z; acc += p4.w*w4.w;
  }
  acc += fc_b[t];
  const int b = gg >> 9, s = gg & 511;
  fcout[((size_t)b*CS + s)*CO + t] = acc;
}

// ---------------------------------------------------------------- linear interp S -> N
__global__ __launch_bounds__(256)
void interp_kernel(const float* __restrict__ fcout, float* __restrict__ out1)
{
  const int idx = blockIdx.x*256 + threadIdx.x;
  const int n  = idx & (CN-1);
  const int bo = idx >> 13;
  const int b  = bo >> 8, o = bo & 255;
  const double pos = (double)n * ((double)(CS-1)/(double)(CN-1));
  const int i0 = (int)pos;
  const int i1 = min(i0+1, CS-1);
  const float w = (float)(pos - (double)i0);
  const float v0 = fcout[((size_t)b*CS + i0)*CO + o];
  const float v1 = fcout[((size_t)b*CS + i1)*CO + o];
  out1[idx] = v0*(1.f - w) + v1*w;
}

// ---------------------------------------------------------------- launcher
extern "C" void kernel_launch(void* const* d_in, const int* in_sizes, int n_in,
                              void* d_out, int out_size, void* d_ws, size_t ws_size,
                              hipStream_t stream)
{
  (void)in_sizes; (void)n_in; (void)out_size;
  const float* xyz      = (const float*)d_in[0];
  const float* features = (const float*)d_in[1];
  const float* pe_w1    = (const float*)d_in[2];
  const float* pe_b1    = (const float*)d_in[3];
  const float* bn_g     = (const float*)d_in[4];
  const float* bn_b     = (const float*)d_in[5];
  const float* bn_m     = (const float*)d_in[6];
  const float* bn_v     = (const float*)d_in[7];
  const float* pe_w2    = (const float*)d_in[8];
  const float* pe_b2    = (const float*)d_in[9];
  const float* wqkv     = (const float*)d_in[10];
  const float* bqkv     = (const float*)d_in[11];
  const float* wo       = (const float*)d_in[12];
  const float* bo       = (const float*)d_in[13];
  const float* g1       = (const float*)d_in[14];
  const float* b1       = (const float*)d_in[15];
  const float* w1       = (const float*)d_in[16];
  const float* bf1      = (const float*)d_in[17];
  const float* w2       = (const float*)d_in[18];
  const float* bf2      = (const float*)d_in[19];
  const float* g2       = (const float*)d_in[20];
  const float* b2       = (const float*)d_in[21];
  const float* fc_w     = (const float*)d_in[22];
  const float* fc_b     = (const float*)d_in[23];

  char* ws = (char*)d_ws;
  int*    fps_idx = (int*)(ws);                               // 16 KB
  int*    gidx    = (int*)(ws + (16u<<10));                   // 512 KB
  ushort* wfrag   = (ushort*)(ws + (1u<<20));                 // 1 MB
  float*  xbuf    = (float*)(ws + (2u<<20));                  // 64 MB
  float*  fcout   = (float*)(ws + (66u<<20));                 // 4 MB
  float*  featT   = (float*)(ws + (70u<<20));                 // 32 MB (optional)
  const bool useT = ws_size >= ((size_t)102<<20);

  float* out0 = (float*)d_out;
  float* out1 = out0 + CB*3*CS;

  fps_kernel<<<CB, 512, 0, stream>>>(xyz, fps_idx);
  knn_kernel<<<CB*CS, 256, 0, stream>>>(xyz, fps_idx, gidx);
  newxyz_kernel<<<(CB*3*CS + 255)/256, 256, 0, stream>>>(xyz, fps_idx, out0);
  wprep_kernel<<<256, 256, 0, stream>>>(wqkv, wo, w1, w2, wfrag);
  if (useT){
    dim3 tb(32, 8), tg(CN/32, CD/32, CB);
    transpose_kernel<<<tg, tb, 0, stream>>>(features, featT);
  }
  pe_kernel<<<CB*CS, 256, 0, stream>>>(xyz, features, useT ? featT : nullptr, gidx,
                                       pe_w1, pe_b1, bn_g, bn_b, bn_m, bn_v,
                                       pe_w2, pe_b2, xbuf);
  for (int L=0; L<4; L++){
    layer_mfma_kernel<<<CB*CS, 256, 0, stream>>>(xbuf,
        wfrag + (size_t)L*131072,
        bqkv + (size_t)L*3*CD, bo + (size_t)L*CD,
        g1 + (size_t)L*CD, b1 + (size_t)L*CD,
        bf1 + (size_t)L*CF, bf2 + (size_t)L*CD,
        g2 + (size_t)L*CD, b2 + (size_t)L*CD);
  }
  poolfc_kernel<<<CB*CS, 256, 0, stream>>>(xbuf, fc_w, fc_b, fcout);
  interp_kernel<<<(CB*CO*CN)/256, 256, 0, stream>>>(fcout, out1);
}

// Round 5
// 1443.032 us; speedup vs baseline: 3.8695x; 1.0268x over previous
//
#include <hip/hip_runtime.h>
#include <math.h>

constexpr int CB  = 8;     // batches
constexpr int CN  = 8192;  // points
constexpr int CS  = 512;   // npoint
constexpr int CK  = 32;    // nsample
constexpr int CD  = 128;   // dim
constexpr int CF  = 256;   // dff
constexpr int CO  = 256;   // dim_out
constexpr float CEPS = 1e-5f;

typedef __attribute__((ext_vector_type(8)))  short short8;
typedef __attribute__((ext_vector_type(4)))  float f32x4;
typedef __attribute__((ext_vector_type(16))) float f32x16;
#define MFMA16(a,b,c) __builtin_amdgcn_mfma_f32_16x16x32_bf16(a,b,c,0,0,0)
#define MFMA32(a,b,c) __builtin_amdgcn_mfma_f32_32x32x16_bf16(a,b,c,0,0,0)

__device__ __forceinline__ ushort f2b(float f){
  unsigned u = __builtin_bit_cast(unsigned, f);
  u = u + 0x7fffu + ((u >> 16) & 1u);
  return (ushort)(u >> 16);
}

// DPP permute of a u64, masked lanes keep their own value (old = self).
template<int CTRL, int RM>
__device__ __forceinline__ unsigned long long dpp64(unsigned long long k){
  int lo = (int)(unsigned)k;
  int hi = (int)(unsigned)(k >> 32);
  int plo = __builtin_amdgcn_update_dpp(lo, lo, CTRL, RM, 0xF, false);
  int phi = __builtin_amdgcn_update_dpp(hi, hi, CTRL, RM, 0xF, false);
  return ((unsigned long long)(unsigned)phi << 32) | (unsigned)plo;
}
// full-wave max; result in lane 63 (use shfl(.,63) to broadcast)
__device__ __forceinline__ unsigned long long wave_max64(unsigned long long k){
  unsigned long long p;
  p = dpp64<0xB1,0xF>(k); k = p > k ? p : k;   // i^1
  p = dpp64<0x4E,0xF>(k); k = p > k ? p : k;   // i^2
  p = dpp64<0x140,0xF>(k); k = p > k ? p : k;  // row mirror
  p = dpp64<0x141,0xF>(k); k = p > k ? p : k;  // half mirror -> row(16) max everywhere
  p = dpp64<0x142,0xA>(k); k = p > k ? p : k;  // bcast15 -> rows 1,3
  p = dpp64<0x143,0xC>(k); k = p > k ? p : k;  // bcast31 -> rows 2,3 ; lane63 full
  return k;
}
__device__ __forceinline__ unsigned long long wave_min64(unsigned long long k){
  unsigned long long p;
  p = dpp64<0xB1,0xF>(k); k = p < k ? p : k;
  p = dpp64<0x4E,0xF>(k); k = p < k ? p : k;
  p = dpp64<0x140,0xF>(k); k = p < k ? p : k;
  p = dpp64<0x141,0xF>(k); k = p < k ? p : k;
  p = dpp64<0x142,0xA>(k); k = p < k ? p : k;
  p = dpp64<0x143,0xC>(k); k = p < k ? p : k;
  return k;
}
// butterfly over 8 replicated values in lanes (l&7) -> all lanes get extreme
__device__ __forceinline__ unsigned long long oct_max64(unsigned long long k){
  unsigned long long p;
  p = dpp64<0xB1,0xF>(k); k = p > k ? p : k;
  p = dpp64<0x4E,0xF>(k); k = p > k ? p : k;
  p = dpp64<0x141,0xF>(k); k = p > k ? p : k;  // i^7 crosses the 4-groups
  return k;
}
__device__ __forceinline__ unsigned long long quad_min64(unsigned long long k){
  unsigned long long p;
  p = dpp64<0xB1,0xF>(k); k = p < k ? p : k;
  p = dpp64<0x4E,0xF>(k); k = p < k ? p : k;
  return k;
}

// ---------------------------------------------------------------- FPS v4
// 512 thr x 16 pts in regs; DPP wave reduce; one barrier/iter (parity LDS).
__global__ __launch_bounds__(512)
void fps_kernel(const float* __restrict__ xyz, int* __restrict__ fps_idx)
{
#pragma clang fp contract(off)
  __shared__ __align__(16) float4 p4[CN];
  __shared__ unsigned long long wred[2][8];
  const int b = blockIdx.x, t = threadIdx.x;
  const int w = t >> 6, lane = t & 63;
  const float* xb = xyz + (size_t)b*3*CN;
  float px[16], py[16], pz[16], dist[16];
  #pragma unroll
  for (int j=0;j<16;j++){
    const int i = t + 512*j;
    px[j] = xb[i]; py[j] = xb[CN+i]; pz[j] = xb[2*CN+i];
    dist[j] = 1e10f;
    p4[i] = make_float4(px[j], py[j], pz[j], 0.f);
  }
  __syncthreads();
  int far = 0, par = 0;
  float4 c = p4[0];
  for (int it = 0; it < CS; ++it){
    if (t == 0) fps_idx[b*CS + it] = far;
    unsigned long long kk[16];
    #pragma unroll
    for (int j=0;j<16;j++){
      const float dx = px[j]-c.x, dy = py[j]-c.y, dz = pz[j]-c.z;
      const float d2 = (dx*dx + dy*dy) + dz*dz;
      const float nd = fminf(dist[j], d2);
      dist[j] = nd;
      kk[j] = ((unsigned long long)__builtin_bit_cast(unsigned, nd) << 32)
              | (unsigned)(8191 - (t + 512*j));
    }
    #pragma unroll
    for (int st=1; st<16; st<<=1)
      #pragma unroll
      for (int j=0;j<16;j+=2*st)
        kk[j] = kk[j] >= kk[j+st] ? kk[j] : kk[j+st];
    unsigned long long key = wave_max64(kk[0]);
    key = __shfl(key, 63);
    if (lane == 0) wred[par][w] = key;
    __syncthreads();
    unsigned long long k2 = wred[par][lane & 7];
    k2 = oct_max64(k2);
    far = 8191 - (int)(k2 & 0xFFFFFFFFu);
    c = p4[far];
    par ^= 1;
  }
}

// ---------------------------------------------------------------- kNN v2
// u64 keys (ordered fp bits | idx); DPP min-reduce; one barrier per round.
__global__ __launch_bounds__(256)
void knn_kernel(const float* __restrict__ xyz, const int* __restrict__ fps_idx,
                int* __restrict__ gidx)
{
#pragma clang fp contract(off)
  __shared__ unsigned long long wredk[2][4];
  const int blk = blockIdx.x, t = threadIdx.x;
  const int w = t >> 6, l = t & 63;
  const int b = blk >> 9;
  const int s = blk & 511;
  const float* xb = xyz + (size_t)b*3*CN;
  const int cidx = fps_idx[b*CS + s];
  const float cx = xb[cidx], cy = xb[CN+cidx], cz = xb[2*CN+cidx];
  const float cn2 = (cx*cx + cy*cy) + cz*cz;
  unsigned long long kv[32];
  #pragma unroll
  for (int j=0;j<32;j++){
    const int i = t + 256*j;
    const float x = xb[i], y = xb[CN+i], z = xb[2*CN+i];
    const float pn2 = (x*x + y*y) + z*z;
    const float dot = (cx*x + cy*y) + cz*z;
    const float d2 = (cn2 + pn2) - 2.0f*dot;
    unsigned u = __builtin_bit_cast(unsigned, d2);
    u ^= (unsigned)((int)u >> 31) | 0x80000000u;   // total order incl. negatives
    kv[j] = ((unsigned long long)u << 32) | (unsigned)i;
  }
  unsigned long long mv;
  {
    unsigned long long tmp[16];
    #pragma unroll
    for (int j=0;j<16;j++) tmp[j] = kv[j] < kv[j+16] ? kv[j] : kv[j+16];
    #pragma unroll
    for (int st=8; st>=1; st>>=1)
      #pragma unroll
      for (int j=0;j<st;j++) tmp[j] = tmp[j] < tmp[j+st] ? tmp[j] : tmp[j+st];
    mv = tmp[0];
  }
  int par = 0;
  for (int k=0;k<CK;k++){
    unsigned long long v = wave_min64(mv);
    v = __shfl(v, 63);
    if (l == 0) wredk[par][w] = v;
    __syncthreads();
    unsigned long long k2 = wredk[par][l & 3];
    k2 = quad_min64(k2);
    const int win = (int)(k2 & 0xFFFFFFFFu);
    if (t == 0) gidx[(size_t)blk*CK + k] = win;
    if ((win & 255) == t){
      const int jw = win >> 8;
      #pragma unroll
      for (int j=0;j<32;j++) if (j == jw) kv[j] = ~0ull;
      unsigned long long tmp[16];
      #pragma unroll
      for (int j=0;j<16;j++) tmp[j] = kv[j] < kv[j+16] ? kv[j] : kv[j+16];
      #pragma unroll
      for (int st=8; st>=1; st>>=1)
        #pragma unroll
        for (int j=0;j<st;j++) tmp[j] = tmp[j] < tmp[j+st] ? tmp[j] : tmp[j+st];
      mv = tmp[0];
    }
    par ^= 1;
  }
}

// ---------------------------------------------------------------- new_xyz out
__global__ __launch_bounds__(256)
void newxyz_kernel(const float* __restrict__ xyz, const int* __restrict__ fps_idx,
                   float* __restrict__ out0)
{
  const int idx = blockIdx.x*256 + threadIdx.x;
  if (idx >= CB*3*CS) return;
  const int s = idx & 511;
  const int c = (idx >> 9) % 3;
  const int b = idx / (3*CS);
  const int n = fps_idx[b*CS + s];
  out0[idx] = xyz[(size_t)b*3*CN + (size_t)c*CN + n];
}

// ---------------------------------------------------------------- feature transpose [B,D,N] -> [B,N,D]
__global__ __launch_bounds__(256)
void transpose_kernel(const float* __restrict__ f, float* __restrict__ ft)
{
  __shared__ float tile[32][33];
  const int b = blockIdx.z, d0 = blockIdx.y*32, n0 = blockIdx.x*32;
  const int tx = threadIdx.x, ty = threadIdx.y;
  const float* fb = f + (size_t)b*CD*CN;
  #pragma unroll
  for (int r=0;r<32;r+=8) tile[ty+r][tx] = fb[(size_t)(d0+ty+r)*CN + n0+tx];
  __syncthreads();
  float* ftb = ft + (size_t)b*CN*CD;
  #pragma unroll
  for (int r=0;r<32;r+=8) ftb[(size_t)(n0+ty+r)*CD + d0+tx] = tile[tx][ty+r];
}

// ---------------------------------------------------------------- gather + PE (4x4 register tile)
__global__ __launch_bounds__(256)
void pe_kernel(const float* __restrict__ xyz, const float* __restrict__ features,
               const float* __restrict__ featT, const int* __restrict__ gidx,
               const float* __restrict__ pe_w1, const float* __restrict__ pe_b1,
               const float* __restrict__ bn_g, const float* __restrict__ bn_b,
               const float* __restrict__ bn_m, const float* __restrict__ bn_v,
               const float* __restrict__ pe_w2, const float* __restrict__ pe_b2,
               float* __restrict__ xout)
{
  __shared__ __align__(16) float w2s[CD*68];
  __shared__ __align__(16) float hr[CK*68];
  __shared__ int idxs[CK];
  __shared__ float gx[CK], gy[CK], gz[CK];
  const int g = blockIdx.x, t = threadIdx.x;
  const int b = g >> 9;
  for (int i=t; i<CD*64; i+=256) w2s[(i>>6)*68 + (i&63)] = pe_w2[i];
  if (t < CK){
    const int id = gidx[(size_t)g*CK + t];
    idxs[t] = id;
    const float* xb = xyz + (size_t)b*3*CN;
    gx[t] = xb[id]; gy[t] = xb[CN+id]; gz[t] = xb[2*CN+id];
  }
  __syncthreads();
  for (int v=t; v<CK*64; v+=256){
    const int k = v>>6, j = v&63;
    float h = ((gx[k]*pe_w1[j*3] + gy[k]*pe_w1[j*3+1]) + gz[k]*pe_w1[j*3+2]) + pe_b1[j];
    h = (h - bn_m[j]) / sqrtf(bn_v[j] + CEPS) * bn_g[j] + bn_b[j];
    hr[k*68+j] = fmaxf(h, 0.f);
  }
  __syncthreads();
  const int kt = t >> 5, dt = t & 31;
  const int k0 = kt*4, d0 = dt*4;
  float acc[4][4];
  #pragma unroll
  for (int a=0;a<4;a++)
    #pragma unroll
    for (int bb=0;bb<4;bb++) acc[a][bb] = 0.f;
  for (int j=0;j<16;j++){
    float4 h4[4], w4[4];
    #pragma unroll
    for (int a=0;a<4;a++) h4[a] = *(const float4*)&hr[(k0+a)*68 + j*4];
    #pragma unroll
    for (int bb=0;bb<4;bb++) w4[bb] = *(const float4*)&w2s[(d0+bb)*68 + j*4];
    #pragma unroll
    for (int a=0;a<4;a++)
      #pragma unroll
      for (int bb=0;bb<4;bb++){
        acc[a][bb] += h4[a].x*w4[bb].x; acc[a][bb] += h4[a].y*w4[bb].y;
        acc[a][bb] += h4[a].z*w4[bb].z; acc[a][bb] += h4[a].w*w4[bb].w;
      }
  }
  const float4 b2v = *(const float4*)&pe_b2[d0];
  const float* fb  = features + (size_t)b*CD*CN;
  const float* ftb = featT ? (featT + (size_t)b*CN*CD) : nullptr;
  #pragma unroll
  for (int a=0;a<4;a++){
    const int id = idxs[k0+a];
    float4 gf;
    if (ftb) gf = *(const float4*)&ftb[(size_t)id*CD + d0];
    else gf = make_float4(fb[(size_t)(d0+0)*CN+id], fb[(size_t)(d0+1)*CN+id],
                          fb[(size_t)(d0+2)*CN+id], fb[(size_t)(d0+3)*CN+id]);
    float4 o;
    o.x = gf.x + (acc[a][0] + b2v.x);
    o.y = gf.y + (acc[a][1] + b2v.y);
    o.z = gf.z + (acc[a][2] + b2v.z);
    o.w = gf.w + (acc[a][3] + b2v.w);
    *(float4*)&xout[(size_t)g*4096 + (size_t)(k0+a)*128 + d0] = o;
  }
}

// ---------------------------------------------------------------- weight prep -> bf16 MFMA B-fragments
__global__ __launch_bounds__(256)
void wprep_kernel(const float* __restrict__ wqkv, const float* __restrict__ wo,
                  const float* __restrict__ w1,   const float* __restrict__ w2,
                  ushort* __restrict__ dst)
{
  const int tid = blockIdx.x*256 + threadIdx.x;   // 65536 threads
  const int l = tid & 63;
  const int f = tid >> 6;          // 0..1023
  const int L = f >> 8;
  const int r = f & 255;
  const float* src; int stride, nt, kt;
  if (r < 96)      { nt = r>>2;        kt = r&3;        src = wqkv + (size_t)L*384*128; stride = 128; }
  else if (r < 128){ nt = (r-96)>>2;   kt = (r-96)&3;   src = wo   + (size_t)L*128*128; stride = 128; }
  else if (r < 192){ nt = (r-128)>>2;  kt = (r-128)&3;  src = w1   + (size_t)L*256*128; stride = 128; }
  else             { nt = (r-192)>>3;  kt = (r-192)&7;  src = w2   + (size_t)L*128*256; stride = 256; }
  const int n = nt*16 + (l & 15);
  const int k = kt*32 + (l >> 4)*8;
  const float* p = src + (size_t)n*stride + k;
  uint4 o;
  o.x = (unsigned)f2b(p[0]) | ((unsigned)f2b(p[1])<<16);
  o.y = (unsigned)f2b(p[2]) | ((unsigned)f2b(p[3])<<16);
  o.z = (unsigned)f2b(p[4]) | ((unsigned)f2b(p[5])<<16);
  o.w = (unsigned)f2b(p[6]) | ((unsigned)f2b(p[7])<<16);
  *(uint4*)(dst + (size_t)tid*8) = o;
}

// ---------------------------------------------------------------- fused MFMA transformer layer
__device__ __forceinline__ void ln_inplace(float* x32s, ushort* xbv,
                                           const float* __restrict__ gamma,
                                           const float* __restrict__ beta, int t)
{
  const int r = t >> 3, j = t & 7;
  float v[16]; float s = 0.f;
  #pragma unroll
  for (int i=0;i<16;i++){ v[i] = x32s[r*132 + j + 8*i]; s += v[i]; }
  #pragma unroll
  for (int off=1; off<8; off<<=1) s += __shfl_xor(s, off);
  const float mean = s * (1.f/128.f);
  float var = 0.f;
  #pragma unroll
  for (int i=0;i<16;i++){ const float d = v[i]-mean; var += d*d; }
  #pragma unroll
  for (int off=1; off<8; off<<=1) var += __shfl_xor(var, off);
  const float inv = 1.f / sqrtf(var*(1.f/128.f) + CEPS);
  #pragma unroll
  for (int i=0;i<16;i++){
    const int d = j + 8*i;
    const float o = (v[i]-mean)*inv*gamma[d] + beta[d];
    x32s[r*132 + d] = o;
    xbv[r*136 + d] = f2b(o);
  }
}

__global__ __launch_bounds__(256, 2)
void layer_mfma_kernel(float* __restrict__ xbuf, const ushort* __restrict__ wf,
                       const float* __restrict__ bqkv, const float* __restrict__ bo,
                       const float* __restrict__ g1, const float* __restrict__ b1v,
                       const float* __restrict__ bf1, const float* __restrict__ bf2,
                       const float* __restrict__ g2, const float* __restrict__ b2v)
{
  __shared__ __align__(16) float  x32s[32*132];   // fp32 residual path
  __shared__ __align__(16) ushort xbv [32*136];   // bf16 A-operand buffer
  __shared__ __align__(16) ushort qk  [32*264];   // Q|K, later FFN1 out
  __shared__ __align__(16) ushort vT  [128*40];   // V transposed [dim][token]
  __shared__ __align__(16) ushort Pb  [4*32*40];  // per-wave P scratch
  const int g = blockIdx.x, t = threadIdx.x;
  const int w = t>>6, l = t&63;
  const int l15 = l&15, q4 = l>>4, l31 = l&31, hi = l>>5;
  float* xg = xbuf + (size_t)g*1024*4;
  const uint4* wfv = (const uint4*)wf;

  for (int i=t;i<1024;i+=256){
    const float4 v = ((const float4*)xg)[i];
    const int r = i>>5, c = (i&31)*4;
    *(float4*)&x32s[r*132 + c] = v;
    uint2 p;
    p.x = (unsigned)f2b(v.x) | ((unsigned)f2b(v.y)<<16);
    p.y = (unsigned)f2b(v.z) | ((unsigned)f2b(v.w)<<16);
    *(uint2*)&xbv[r*136 + c] = p;
  }
  __syncthreads();

  // ---- QKV
  {
    short8 a[2][4];
    #pragma unroll
    for (int mt=0;mt<2;mt++)
      #pragma unroll
      for (int kt=0;kt<4;kt++)
        a[mt][kt] = __builtin_bit_cast(short8, *(const uint4*)&xbv[(l15+16*mt)*136 + kt*32 + q4*8]);
    for (int i=0;i<6;i++){
      const int nt = w + 4*i;
      const int n  = nt*16 + l15;
      f32x4 a0 = {0.f,0.f,0.f,0.f}, a1 = {0.f,0.f,0.f,0.f};
      #pragma unroll
      for (int kt=0;kt<4;kt++){
        const short8 b = __builtin_bit_cast(short8, wfv[(nt*4+kt)*64 + l]);
        a0 = MFMA16(a[0][kt], b, a0);
        a1 = MFMA16(a[1][kt], b, a1);
      }
      const float bias = bqkv[n];
      if (nt < 16){
        #pragma unroll
        for (int i2=0;i2<4;i2++){
          qk[(q4*4+i2   )*264 + n] = f2b(a0[i2]+bias);
          qk[(q4*4+i2+16)*264 + n] = f2b(a1[i2]+bias);
        }
      } else {
        const int d = n - 256;
        uint2 p0, p1;
        p0.x = (unsigned)f2b(a0[0]+bias) | ((unsigned)f2b(a0[1]+bias)<<16);
        p0.y = (unsigned)f2b(a0[2]+bias) | ((unsigned)f2b(a0[3]+bias)<<16);
        p1.x = (unsigned)f2b(a1[0]+bias) | ((unsigned)f2b(a1[1]+bias)<<16);
        p1.y = (unsigned)f2b(a1[2]+bias) | ((unsigned)f2b(a1[3]+bias)<<16);
        *(uint2*)&vT[d*40 + q4*4]      = p0;
        *(uint2*)&vT[d*40 + 16 + q4*4] = p1;
      }
    }
  }
  __syncthreads();

  // ---- attention
  for (int hh=0; hh<2; hh++){
    const int h = 2*w + hh;
    const short8 ka = __builtin_bit_cast(short8, *(const uint4*)&qk[l31*264 + 128 + h*16 + hi*8]);
    const short8 qb = __builtin_bit_cast(short8, *(const uint4*)&qk[l31*264 +       h*16 + hi*8]);
    f32x16 s;
    #pragma unroll
    for (int i=0;i<16;i++) s[i] = 0.f;
    s = MFMA32(ka, qb, s);
    float e[16]; float mx = -1e30f;
    #pragma unroll
    for (int i=0;i<16;i++){ e[i] = s[i]*0.25f; mx = fmaxf(mx, e[i]); }
    mx = fmaxf(mx, __shfl_xor(mx, 32));
    float sum = 0.f;
    #pragma unroll
    for (int i=0;i<16;i++){ e[i] = __expf(e[i]-mx); sum += e[i]; }
    sum += __shfl_xor(sum, 32);
    const float inv = 1.f/sum;
    #pragma unroll
    for (int j=0;j<4;j++){
      uint2 p;
      p.x = (unsigned)f2b(e[4*j  ]*inv) | ((unsigned)f2b(e[4*j+1]*inv)<<16);
      p.y = (unsigned)f2b(e[4*j+2]*inv) | ((unsigned)f2b(e[4*j+3]*inv)<<16);
      *(uint2*)&Pb[w*1280 + l31*40 + j*8 + hi*4] = p;
    }
    const short8 bv = __builtin_bit_cast(short8, *(const uint4*)&vT[(h*16+l15)*40 + q4*8]);
    #pragma unroll
    for (int mt=0;mt<2;mt++){
      const short8 ap = __builtin_bit_cast(short8, *(const uint4*)&Pb[w*1280 + (l15+16*mt)*40 + q4*8]);
      f32x4 o = {0.f,0.f,0.f,0.f};
      o = MFMA16(ap, bv, o);
      #pragma unroll
      for (int i2=0;i2<4;i2++)
        xbv[(16*mt + q4*4 + i2)*136 + h*16 + l15] = f2b(o[i2]);
    }
  }
  __syncthreads();

  // ---- O-proj + residual
  {
    short8 a[2][4];
    #pragma unroll
    for (int mt=0;mt<2;mt++)
      #pragma unroll
      for (int kt=0;kt<4;kt++)
        a[mt][kt] = __builtin_bit_cast(short8, *(const uint4*)&xbv[(l15+16*mt)*136 + kt*32 + q4*8]);
    for (int i=0;i<2;i++){
      const int nt = w + 4*i;
      const int n  = nt*16 + l15;
      f32x4 a0 = {0.f,0.f,0.f,0.f}, a1 = {0.f,0.f,0.f,0.f};
      #pragma unroll
      for (int kt=0;kt<4;kt++){
        const short8 b = __builtin_bit_cast(short8, wfv[(96 + nt*4+kt)*64 + l]);
        a0 = MFMA16(a[0][kt], b, a0);
        a1 = MFMA16(a[1][kt], b, a1);
      }
      const float bias = bo[n];
      #pragma unroll
      for (int i2=0;i2<4;i2++){
        x32s[(q4*4+i2   )*132 + n] += a0[i2] + bias;
        x32s[(q4*4+i2+16)*132 + n] += a1[i2] + bias;
      }
    }
  }
  __syncthreads();
  ln_inplace(x32s, xbv, g1, b1v, t);
  __syncthreads();

  // ---- FFN1 + relu
  {
    short8 a[2][4];
    #pragma unroll
    for (int mt=0;mt<2;mt++)
      #pragma unroll
      for (int kt=0;kt<4;kt++)
        a[mt][kt] = __builtin_bit_cast(short8, *(const uint4*)&xbv[(l15+16*mt)*136 + kt*32 + q4*8]);
    for (int i=0;i<4;i++){
      const int nt = w + 4*i;
      const int n  = nt*16 + l15;
      f32x4 a0 = {0.f,0.f,0.f,0.f}, a1 = {0.f,0.f,0.f,0.f};
      #pragma unroll
      for (int kt=0;kt<4;kt++){
        const short8 b = __builtin_bit_cast(short8, wfv[(128 + nt*4+kt)*64 + l]);
        a0 = MFMA16(a[0][kt], b, a0);
        a1 = MFMA16(a[1][kt], b, a1);
      }
      const float bias = bf1[n];
      #pragma unroll
      for (int i2=0;i2<4;i2++){
        qk[(q4*4+i2   )*264 + n] = f2b(fmaxf(a0[i2]+bias, 0.f));
        qk[(q4*4+i2+16)*264 + n] = f2b(fmaxf(a1[i2]+bias, 0.f));
      }
    }
  }
  __syncthreads();

  // ---- FFN2 + residual, K=256
  {
    short8 a[2][8];
    #pragma unroll
    for (int mt=0;mt<2;mt++)
      #pragma unroll
      for (int kt=0;kt<8;kt++)
        a[mt][kt] = __builtin_bit_cast(short8, *(const uint4*)&qk[(l15+16*mt)*264 + kt*32 + q4*8]);
    for (int i=0;i<2;i++){
      const int nt = w + 4*i;
      const int n  = nt*16 + l15;
      f32x4 a0 = {0.f,0.f,0.f,0.f}, a1 = {0.f,0.f,0.f,0.f};
      #pragma unroll
      for (int kt=0;kt<8;kt++){
        const short8 b = __builtin_bit_cast(short8, wfv[(192 + nt*8+kt)*64 + l]);
        a0 = MFMA16(a[0][kt], b, a0);
        a1 = MFMA16(a[1][kt], b, a1);
      }
      const float bias = bf2[n];
      #pragma unroll
      for (int i2=0;i2<4;i2++){
        x32s[(q4*4+i2   )*132 + n] += a0[i2] + bias;
        x32s[(q4*4+i2+16)*132 + n] += a1[i2] + bias;
      }
    }
  }
  __syncthreads();
  ln_inplace(x32s, xbv, g2, b2v, t);
  __syncthreads();

  for (int i=t;i<1024;i+=256){
    const int r = i>>5, c = (i&31)*4;
    ((float4*)xg)[i] = *(const float4*)&x32s[r*132 + c];
  }
}

// ---------------------------------------------------------------- max-pool + fc
__global__ __launch_bounds__(256)
void poolfc_kernel(const float* __restrict__ xbuf, const float* __restrict__ fc_w,
                   const float* __restrict__ fc_b, float* __restrict__ fcout)
{
  __shared__ __align__(16) float pooled[CD];
  const int gg = blockIdx.x, t = threadIdx.x;
  const float* xg = xbuf + (size_t)gg*CK*CD;
  if (t < CD){
    float m = -1e30f;
    for (int k=0;k<CK;k++) m = fmaxf(m, xg[(size_t)k*CD + t]);
    pooled[t] = m;
  }
  __syncthreads();
  const float* wr = fc_w + (size_t)t*CD;
  float acc = 0.f;
  const float4* pp = (const float4*)pooled;
  for (int i=0;i<CD/4;i++){
    const float4 w4 = *(const float4*)(wr + 4*i);
    const float4 p4 = pp[i];
    acc += p4.x*w4.x; acc += p4.y*w4.y; acc += p4.z*w4.z; acc += p4.w*w4.w;
  }
  acc += fc_b[t];
  const int b = gg >> 9, s = gg & 511;
  fcout[((size_t)b*CS + s)*CO + t] = acc;
}

// ---------------------------------------------------------------- linear interp S -> N
__global__ __launch_bounds__(256)
void interp_kernel(const float* __restrict__ fcout, float* __restrict__ out1)
{
  const int idx = blockIdx.x*256 + threadIdx.x;
  const int n  = idx & (CN-1);
  const int bo = idx >> 13;
  const int b  = bo >> 8, o = bo & 255;
  const double pos = (double)n * ((double)(CS-1)/(double)(CN-1));
  const int i0 = (int)pos;
  const int i1 = min(i0+1, CS-1);
  const float w = (float)(pos - (double)i0);
  const float v0 = fcout[((size_t)b*CS + i0)*CO + o];
  const float v1 = fcout[((size_t)b*CS + i1)*CO + o];
  out1[idx] = v0*(1.f - w) + v1*w;
}

// ---------------------------------------------------------------- launcher
extern "C" void kernel_launch(void* const* d_in, const int* in_sizes, int n_in,
                              void* d_out, int out_size, void* d_ws, size_t ws_size,
                              hipStream_t stream)
{
  (void)in_sizes; (void)n_in; (void)out_size;
  const float* xyz      = (const float*)d_in[0];
  const float* features = (const float*)d_in[1];
  const float* pe_w1    = (const float*)d_in[2];
  const float* pe_b1    = (const float*)d_in[3];
  const float* bn_g     = (const float*)d_in[4];
  const float* bn_b     = (const float*)d_in[5];
  const float* bn_m     = (const float*)d_in[6];
  const float* bn_v     = (const float*)d_in[7];
  const float* pe_w2    = (const float*)d_in[8];
  const float* pe_b2    = (const float*)d_in[9];
  const float* wqkv     = (const float*)d_in[10];
  const float* bqkv     = (const float*)d_in[11];
  const float* wo       = (const float*)d_in[12];
  const float* bo       = (const float*)d_in[13];
  const float* g1       = (const float*)d_in[14];
  const float* b1       = (const float*)d_in[15];
  const float* w1       = (const float*)d_in[16];
  const float* bf1      = (const float*)d_in[17];
  const float* w2       = (const float*)d_in[18];
  const float* bf2      = (const float*)d_in[19];
  const float* g2       = (const float*)d_in[20];
  const float* b2       = (const float*)d_in[21];
  const float* fc_w     = (const float*)d_in[22];
  const float* fc_b     = (const float*)d_in[23];

  char* ws = (char*)d_ws;
  int*    fps_idx = (int*)(ws);                               // 16 KB
  int*    gidx    = (int*)(ws + (16u<<10));                   // 512 KB
  ushort* wfrag   = (ushort*)(ws + (1u<<20));                 // 1 MB
  float*  xbuf    = (float*)(ws + (2u<<20));                  // 64 MB
  float*  fcout   = (float*)(ws + (66u<<20));                 // 4 MB
  float*  featT   = (float*)(ws + (70u<<20));                 // 32 MB (optional)
  const bool useT = ws_size >= ((size_t)102<<20);

  float* out0 = (float*)d_out;
  float* out1 = out0 + CB*3*CS;

  fps_kernel<<<CB, 512, 0, stream>>>(xyz, fps_idx);
  knn_kernel<<<CB*CS, 256, 0, stream>>>(xyz, fps_idx, gidx);
  newxyz_kernel<<<(CB*3*CS + 255)/256, 256, 0, stream>>>(xyz, fps_idx, out0);
  wprep_kernel<<<256, 256, 0, stream>>>(wqkv, wo, w1, w2, wfrag);
  if (useT){
    dim3 tb(32, 8), tg(CN/32, CD/32, CB);
    transpose_kernel<<<tg, tb, 0, stream>>>(features, featT);
  }
  pe_kernel<<<CB*CS, 256, 0, stream>>>(xyz, features, useT ? featT : nullptr, gidx,
                                       pe_w1, pe_b1, bn_g, bn_b, bn_m, bn_v,
                                       pe_w2, pe_b2, xbuf);
  for (int L=0; L<4; L++){
    layer_mfma_kernel<<<CB*CS, 256, 0, stream>>>(xbuf,
        wfrag + (size_t)L*131072,
        bqkv + (size_t)L*3*CD, bo + (size_t)L*CD,
        g1 + (size_t)L*CD, b1 + (size_t)L*CD,
        bf1 + (size_t)L*CF, bf2 + (size_t)L*CD,
        g2 + (size_t)L*CD, b2 + (size_t)L*CD);
  }
  poolfc_kernel<<<CB*CS, 256, 0, stream>>>(xbuf, fc_w, fc_b, fcout);
  interp_kernel<<<(CB*CO*CN)/256, 256, 0, stream>>>(fcout, out1);
}